// Round 4
// baseline (930.219 us; speedup 1.0000x reference)
//
#include <hip/hip_runtime.h>
#include <hip/hip_bf16.h>
#include <math.h>

// B=8 N=196 D=512 M=20 K=77 H=8 hd=64, keep=51.  All inputs/outputs fp32.
// out1 = Qs/nrm (B,N,D,M) 16,056,320 fl; out2 = attn_weights (B,K,N) 120,736 fl
// Workspace (fp32 words):
//  WT @0:786432  OWT @786432:262144  q @1048576:39424  kmat @1088000:802816
//  vmat @1890816:802816  attf @2693632:965888  attw @3659520:120736
//  ctx @3780256:315392  AO @4095648:315392  Qp @4411040:62720 (2 halves x 20/bn)
//  W1hi(fp16) @4473760: 131072 fl  W1lo(fp16) @4604832: 131072 fl -> 4735904 fl = 18.9 MB
//  Reuse after consumers finish: wsum -> qws region, Sv -> kmat region (dead after k3)
//
// R10 change (evidence: R0/R7/R8/R9 all ~355-380us regardless of occupancy/
// spill/VGPR -> limiter is the 16x per-block __syncthreads + vmcnt(0) drain +
// 8-way-conflicted ds_write staging, not registers):
//  k7 t-loop is now BARRIER-FREE. Each lane computes its own A-fragment
//  directly from AO/FvK/Sv (8 consecutive d's) instead of staging the clean
//  matrix through LDS. No Ah/Al arrays, no double-buffer, no per-step sync.
//  MFMA floor ~114us; VALU for redundant A-compute ~1360 cyc/SIMD-layer vs
//  MFMA 2800 -> hidden. LDS pad 62KB kept (R9-proven: 2 blk/CU -> VGPR cap 128).

typedef unsigned int uint;
typedef _Float16 f16x8 __attribute__((ext_vector_type(8)));
typedef float f32x4 __attribute__((ext_vector_type(4)));

#define DI __device__ __forceinline__

DI float wsumf(float v){ for(int o=32;o>0;o>>=1) v += __shfl_xor(v,o,64); return v; }
DI int   wsumi(int v){ for(int o=32;o>0;o>>=1) v += __shfl_xor(v,o,64); return v; }
DI float wmaxf(float v){ for(int o=32;o>0;o>>=1) v = fmaxf(v,__shfl_xor(v,o,64)); return v; }

// ---------------- K0: tiled transposes + W1 split/swizzle ----------------
__global__ __launch_bounds__(256) void k0_transpose(const float* ipw, const float* ow, const float* mw1,
                             float* WT, float* OWT, _Float16* w1hi, _Float16* w1lo){
  int bid = blockIdx.x;
  if(bid < 768){
    __shared__ float t[32][33];
    int tdin = bid & 15, tdout = bid >> 4;
    int tx = threadIdx.x & 31, ty = threadIdx.x >> 5;
    int dout0 = tdout*32, din0 = tdin*32;
    for(int r=ty; r<32; r+=8) t[r][tx] = ipw[(size_t)(dout0+r)*512 + din0+tx];
    __syncthreads();
    for(int r=ty; r<32; r+=8) WT[(size_t)(din0+r)*1536 + dout0+tx] = t[tx][r];
  } else if(bid < 1024){
    __shared__ float t[32][33];
    int b2 = bid - 768;
    int tdin = b2 & 15, tdout = b2 >> 4;
    int tx = threadIdx.x & 31, ty = threadIdx.x >> 5;
    int dout0 = tdout*32, din0 = tdin*32;
    for(int r=ty; r<32; r+=8) t[r][tx] = ow[(size_t)(dout0+r)*512 + din0+tx];
    __syncthreads();
    for(int r=ty; r<32; r+=8) OWT[(size_t)(din0+r)*512 + dout0+tx] = t[tx][r];
  } else {
    int i3 = (bid-1024)*256 + threadIdx.x;
    int t = i3&7, ln = (i3>>3)&63, J = (i3>>9)&31, T = i3>>14;
    int j = J*16 + (ln&15);
    int d = T*32 + ((ln>>4)<<3) + t;
    float w = mw1[j*512 + d] * 64.0f;
    _Float16 hi = (_Float16)w;
    _Float16 lo = (_Float16)(w - (float)hi);
    w1hi[i3] = hi; w1lo[i3] = lo;
  }
}

// ---------------- K1: q = LN(text) @ Wq^T + bq  (154 blocks: k x half) ----------------
__global__ __launch_bounds__(256) void k1_q(const float* text, const float* ipb,
                                            const float* g1, const float* b1p,
                                            const float* WT, float* qws){
  int k = blockIdx.x >> 1, half = blockIdx.x & 1;
  int tid = threadIdx.x;
  __shared__ float xln[512];
  __shared__ float rA[4], rB[4];
  float x0 = text[k*512+tid], x1 = text[k*512+256+tid];
  float s1 = wsumf(x0+x1), s2 = wsumf(x0*x0+x1*x1);
  int w = tid>>6, ln = tid&63;
  if(!ln){ rA[w]=s1; rB[w]=s2; }
  __syncthreads();
  float mu = (rA[0]+rA[1]+rA[2]+rA[3])*(1.f/512.f);
  float var = (rB[0]+rB[1]+rB[2]+rB[3])*(1.f/512.f) - mu*mu;
  float rs = 1.f/sqrtf(fmaxf(var,0.f) + 1e-5f);
  xln[tid]     = (x0-mu)*rs*g1[tid]     + b1p[tid];
  xln[tid+256] = (x1-mu)*rs*g1[tid+256] + b1p[tid+256];
  __syncthreads();
  int d = half*256 + tid;
  float a0=0.f,a1=0.f,a2=0.f,a3=0.f;   // 4 independent chains for ILP
  for(int din=0; din<512; din+=4){
    a0 += xln[din  ] * WT[(din  )*1536 + d];
    a1 += xln[din+1] * WT[(din+1)*1536 + d];
    a2 += xln[din+2] * WT[(din+2)*1536 + d];
    a3 += xln[din+3] * WT[(din+3)*1536 + d];
  }
  qws[k*512+d] = ipb[d] + ((a0+a1)+(a2+a3));
}

// ---------------- K2: k = LN(F)@Wk^T+bk, v = F@Wv^T+bv  (512 thr) ----------------
__global__ __launch_bounds__(512) void k2_kv(const float* F, const float* ipb,
                                             const float* g1, const float* b1p,
                                             const float* WT, float* kmat, float* vmat){
  int r0 = blockIdx.x*8; int tid = threadIdx.x;
  __shared__ float xs[8][512];
  __shared__ float xl[8][512];
  __shared__ float red[8][64];
  __shared__ float mu8[8], rs8[8];
  for(int e=tid; e<4096; e+=512){ int r=e>>9, d=e&511; xs[r][d] = F[(size_t)(r0+r)*512 + d]; }
  __syncthreads();
  {
    int r = tid>>6, t = tid&63; float s=0.f, q=0.f;
    for(int i=0;i<8;++i){ float v = xs[r][t+64*i]; s+=v; q+=v*v; }
    red[r][t] = s; __syncthreads();
    if(tid<8){ float ss=0; for(int i=0;i<64;++i) ss+=red[tid][i]; mu8[tid]=ss*(1.f/512.f); }
    __syncthreads();
    red[r][t] = q; __syncthreads();
    if(tid<8){ float qq=0; for(int i=0;i<64;++i) qq+=red[tid][i];
      float m=mu8[tid]; rs8[tid]=1.f/sqrtf(fmaxf(qq*(1.f/512.f)-m*m,0.f)+1e-5f); }
    __syncthreads();
  }
  for(int e=tid; e<4096; e+=512){ int r=e>>9, d=e&511;
    xl[r][d] = (xs[r][d]-mu8[r])*rs8[r]*g1[d] + b1p[d]; }
  __syncthreads();
  int d=tid;
  float ak[8], av[8];
  float bk=ipb[512+d], bv=ipb[1024+d];
  #pragma unroll
  for(int r=0;r<8;++r){ ak[r]=bk; av[r]=bv; }
  for(int din=0; din<512; din+=4){
    float wk[4], wv[4];
    #pragma unroll
    for(int u=0;u<4;++u){ wk[u]=WT[(din+u)*1536+512+d]; wv[u]=WT[(din+u)*1536+1024+d]; }
    #pragma unroll
    for(int r=0;r<8;++r){
      float4 a4 = *(const float4*)&xl[r][din];
      float4 x4 = *(const float4*)&xs[r][din];
      ak[r] += a4.x*wk[0]+a4.y*wk[1]+a4.z*wk[2]+a4.w*wk[3];
      av[r] += x4.x*wv[0]+x4.y*wv[1]+x4.z*wv[2]+x4.w*wv[3];
    }
  }
  #pragma unroll
  for(int r=0;r<8;++r){
    size_t base = (size_t)(r0+r)*512;
    kmat[base+d]=ak[r]; vmat[base+d]=av[r];
  }
}

// ---------------- K3: scores + softmax (640 blocks: kc x b x h) ----------------
__global__ __launch_bounds__(256) void k3_attn(const float* qws, const float* kmat, float* attf){
  int bid = blockIdx.x;
  int kc = bid>>6, b = (bid>>3)&7, h = bid&7;
  int tid = threadIdx.x; int n = tid; int w = tid>>6, ln = tid&63;
  __shared__ float qb[8][64];
  __shared__ float rM[8][4], rS[8][4];
  float4 kr[16];
  if(n < 196){
    const float4* kp = (const float4*)(kmat + ((size_t)(b*196+n))*512 + h*64);
    #pragma unroll
    for(int j=0;j<16;++j) kr[j] = kp[j];
  }
  int kbase = kc*8;
  for(int e=tid; e<512; e+=256){ int kk=e>>6, j=e&63; int k=kbase+kk;
    qb[kk][j] = (k<77)? qws[k*512 + h*64 + j] : 0.f; }
  __syncthreads();
  float sc[8];
  #pragma unroll
  for(int kk=0;kk<8;++kk){
    float s = 0.f;
    if(n<196){
      const float4* q4 = (const float4*)qb[kk];
      #pragma unroll
      for(int j=0;j<16;++j){ float4 q = q4[j];
        s += q.x*kr[j].x + q.y*kr[j].y + q.z*kr[j].z + q.w*kr[j].w; }
      sc[kk] = s*0.125f;
    } else sc[kk] = -INFINITY;
  }
  #pragma unroll
  for(int kk=0;kk<8;++kk){ float m = wmaxf(sc[kk]); if(!ln) rM[kk][w]=m; }
  __syncthreads();
  float ex[8];
  #pragma unroll
  for(int kk=0;kk<8;++kk){
    float m = fmaxf(fmaxf(rM[kk][0],rM[kk][1]),fmaxf(rM[kk][2],rM[kk][3]));
    float e = expf(sc[kk]-m);
    ex[kk]=e;
    float s = wsumf(e); if(!ln) rS[kk][w]=s;
  }
  __syncthreads();
  #pragma unroll
  for(int kk=0;kk<8;++kk){
    int k = kbase+kk;
    if(k<77 && n<196){
      float tot = rS[kk][0]+rS[kk][1]+rS[kk][2]+rS[kk][3];
      attf[(((size_t)(b*8+h))*77 + k)*196 + n] = ex[kk]/tot;
    }
  }
}

// ---------------- K4: ctx = attn @ v (640 blocks: kc x b x h) ----------------
__global__ __launch_bounds__(256) void k4_ctx(const float* attf, const float* vmat, float* ctx){
  int bid = blockIdx.x;
  int kc = bid>>6, b = (bid>>3)&7, h = bid&7;
  int tid = threadIdx.x; int ng = tid>>6, j = tid&63;
  __shared__ float vT[196][64];
  __shared__ float aT[8][196];
  __shared__ float red[8][4][64];
  for(int e=tid; e<196*16; e+=256){ int n=e>>4, jc=e&15;
    const float4* vp = (const float4*)(vmat + ((size_t)(b*196+n))*512 + h*64);
    *(float4*)&vT[n][jc*4] = vp[jc];
  }
  int kbase=kc*8;
  for(int e=tid; e<8*196; e+=256){ int kk=e/196, n=e-kk*196; int k=kbase+kk;
    aT[kk][n] = (k<77)? attf[(((size_t)(b*8+h))*77+k)*196+n] : 0.f; }
  __syncthreads();
  float vr[49];
  #pragma unroll
  for(int t=0;t<49;++t) vr[t] = vT[ng*49+t][j];
  #pragma unroll
  for(int kk=0;kk<8;++kk){
    float p=0.f;
    #pragma unroll
    for(int t=0;t<49;++t) p += aT[kk][ng*49+t]*vr[t];
    red[kk][ng][j]=p;
  }
  __syncthreads();
  for(int e=tid; e<512; e+=256){ int kk=e>>6, j2=e&63; int k=kbase+kk;
    if(k<77){
      float s = red[kk][0][j2]+red[kk][1][j2]+red[kk][2][j2]+red[kk][3][j2];
      ctx[((size_t)(b*77+k))*512 + h*64 + j2] = s;
    } }
}

// ---------------- K5: attn_weights = mean over H ----------------
__global__ void k5_attw(const float* attf, float* attw, float* out2){
  int idx = blockIdx.x*256+threadIdx.x;
  if(idx >= 8*77*196) return;
  int b = idx / (77*196); int rem = idx - b*(77*196);
  float s=0.f;
  #pragma unroll
  for(int h=0;h<8;++h) s += attf[((size_t)(b*8+h))*77*196 + rem];
  s *= 0.125f;
  attw[idx]=s; out2[idx]=s;
}

// ---------------- K6: AO = LN2(ctx @ out_w^T + out_b)  (512 thr) ----------------
__global__ __launch_bounds__(512) void k6_ao(const float* ctx, const float* OWT,
                                             const float* ob, const float* g2, const float* b2p,
                                             float* AO){
  int R0 = blockIdx.x*8; int tid = threadIdx.x;
  __shared__ float xs[8][512];
  __shared__ float ao[8][512];
  __shared__ float red[8][64];
  __shared__ float mu8[8], rs8[8];
  for(int e=tid;e<4096;e+=512){ int r=e>>9,d=e&511; xs[r][d]=ctx[(size_t)(R0+r)*512+d]; }
  __syncthreads();
  int d=tid;
  float a[8]; float obv=ob[d];
  #pragma unroll
  for(int r=0;r<8;++r) a[r]=obv;
  for(int din=0;din<512;din+=4){
    float wv[4];
    #pragma unroll
    for(int u=0;u<4;++u) wv[u]=OWT[(din+u)*512+d];
    #pragma unroll
    for(int r=0;r<8;++r){
      float4 x4 = *(const float4*)&xs[r][din];
      a[r] += x4.x*wv[0]+x4.y*wv[1]+x4.z*wv[2]+x4.w*wv[3];
    }
  }
  #pragma unroll
  for(int r=0;r<8;++r) ao[r][d]=a[r];
  __syncthreads();
  {
    int r=tid>>6,t=tid&63; float s=0.f,q=0.f;
    for(int i=0;i<8;++i){ float v=ao[r][t+64*i]; s+=v; q+=v*v; }
    red[r][t]=s; __syncthreads();
    if(tid<8){ float ss=0; for(int i=0;i<64;++i) ss+=red[tid][i]; mu8[tid]=ss*(1.f/512.f); }
    __syncthreads(); red[r][t]=q; __syncthreads();
    if(tid<8){ float qq=0; for(int i=0;i<64;++i) qq+=red[tid][i];
      float m=mu8[tid]; rs8[tid]=1.f/sqrtf(fmaxf(qq*(1.f/512.f)-m*m,0.f)+1e-5f); }
    __syncthreads();
  }
  for(int e=tid;e<4096;e+=512){ int r=e>>9,dd=e&511;
    AO[(size_t)(R0+r)*512+dd] = (ao[r][dd]-mu8[r])*rs8[r]*g2[dd] + b2p[dd]; }
}

// ---------------- K6b: Sv = (1/77) attw^T @ AO per (b, 8-n tile); wsum ---------
__global__ __launch_bounds__(512) void k6b_sv(const float* AO, const float* attw,
                                              float* Svws, float* wsumws){
  int bid = blockIdx.x;
  int b = bid/25, nt = bid - b*25;
  int n0 = nt*8;
  int tid = threadIdx.x;
  __shared__ float wsK[80][8];
  for(int e=tid; e<640; e+=512){ int k=e>>3, r=e&7; int n=n0+r;
    wsK[k][r] = (k<77 && n<196)? attw[((size_t)(b*77+k))*196 + n] : 0.f; }
  __syncthreads();
  if(tid<8){ int n=n0+tid;
    if(n<196){ float s=0.f;
      for(int k=0;k<77;++k) s+=wsK[k][tid];
      wsumws[b*196+n]=s; } }
  int d = tid;
  float acc[8];
  #pragma unroll
  for(int r=0;r<8;++r) acc[r]=0.f;
  const float* aob = AO + (size_t)b*77*512 + d;
  for(int k=0;k<77;++k){
    float a = aob[(size_t)k*512];
    #pragma unroll
    for(int r=0;r<8;++r) acc[r] += wsK[k][r]*a;
  }
  #pragma unroll
  for(int r=0;r<8;++r){ int n=n0+r; if(n<196)
    Svws[((size_t)(b*196+n))*512 + d] = acc[r]*(1.f/77.f); }
}

// ---------------- K7: per-(b,n,half) fused MLP, barrier-free register A-frags ----
// Row-split: half 0 = rows 0..47 (MT=3), half 1 = rows 48..79 (MT=2).
// Each lane builds its OWN A-fragment (8 consecutive d of row K0+mt*16+col)
// from AO (L1-hot: all waves share the same 6KB/step) + FvK/Sv (LDS b128).
// No LDS A arrays, no double-buffer, NO __syncthreads in the t-loop.
// LDS pad keeps total at 62464B (R9-proven: 2 blk/CU -> backend VGPR cap 128).
struct __align__(16) K7Smem {
  float FvK[512], Sv[512], b1s[512], gs[512], bs[512];
  float wvS[80];
  float redS[8][48], redQ[8][48];
  float mu48[48], rs48[48];
  float gfin[512];
  float qred[320];
  float pad[11280];   // total 62464 B -> 2 blocks/CU -> VGPR cap 128
};

#define K7_MFMA3(ACC, AFH, AFL, BH, BL) \
  ACC = __builtin_amdgcn_mfma_f32_16x16x32_f16(AFL, BH, ACC, 0,0,0); \
  ACC = __builtin_amdgcn_mfma_f32_16x16x32_f16(AFH, BL, ACC, 0,0,0); \
  ACC = __builtin_amdgcn_mfma_f32_16x16x32_f16(AFH, BH, ACC, 0,0,0);

template<int MT, int K0>
DI void k7_body(int bn, const float* F, const float* AO, const float* attw,
                const _Float16* w1hi, const _Float16* w1lo,
                const float* b1p, const float* lng, const float* lnb,
                const float* w2, const float* b2p,
                const float* Svws, const float* wsumws,
                float* Qpws, K7Smem& sm){
  int b = bn/196, n = bn - b*196;
  int tid = threadIdx.x; int w = tid>>6, ln = tid&63;
  int col = ln&15, quad = ln>>4;
  const float* AObase = AO + (size_t)b*77*512;
  sm.FvK[tid] = F[(size_t)bn*512 + tid]*1024.f;
  sm.Sv[tid]  = Svws[(size_t)bn*512 + tid];
  sm.b1s[tid] = b1p[tid]; sm.gs[tid] = lng[tid]; sm.bs[tid] = lnb[tid];
  if(tid<80) sm.wvS[tid] = (tid<77)? attw[((size_t)(b*77+tid))*196+n] : 0.f;
  __syncthreads();

  int lane_d0 = quad*8;                 // this lane's k-slice within the 32-col window
  float wr[MT]; const float* aop[MT];
  #pragma unroll
  for(int mt=0;mt<MT;++mt){
    int row = K0 + mt*16 + col;
    wr[mt] = sm.wvS[row];
    aop[mt] = AObase + (size_t)row*512 + lane_d0;
  }

  f32x4 acc[MT][4];
  #pragma unroll
  for(int mt=0;mt<MT;++mt)
    #pragma unroll
    for(int jj=0;jj<4;++jj) acc[mt][jj] = (f32x4){0.f,0.f,0.f,0.f};

  const _Float16* bph = w1hi + ((w*4)*64 + ln)*8;  // +512 per jj, +16384 per t
  const _Float16* bpl = w1lo + ((w*4)*64 + ln)*8;

  #pragma unroll 1
  for(int t=0; t<16; ++t){
    int d0 = t*32 + lane_d0;
    float4 fv0 = *(const float4*)&sm.FvK[d0];
    float4 fv1 = *(const float4*)&sm.FvK[d0+4];
    float4 sv0 = *(const float4*)&sm.Sv[d0];
    float4 sv1 = *(const float4*)&sm.Sv[d0+4];
    f16x8 Afh[MT], Afl[MT];
    #pragma unroll
    for(int mt=0;mt<MT;++mt){
      float4 a0 = *(const float4*)(aop[mt] + t*32);
      float4 a1 = *(const float4*)(aop[mt] + t*32 + 4);
      float wm = wr[mt];
      float c0 = fv0.x*(wm*a0.x - sv0.x);
      float c1 = fv0.y*(wm*a0.y - sv0.y);
      float c2 = fv0.z*(wm*a0.z - sv0.z);
      float c3 = fv0.w*(wm*a0.w - sv0.w);
      float c4 = fv1.x*(wm*a1.x - sv1.x);
      float c5 = fv1.y*(wm*a1.y - sv1.y);
      float c6 = fv1.z*(wm*a1.z - sv1.z);
      float c7 = fv1.w*(wm*a1.w - sv1.w);
      if(K0==48 && mt==1){              // rows 64..79: mask rows 77..79 (col>=13)
        bool v = col < 13;
        c0 = v?c0:0.f; c1 = v?c1:0.f; c2 = v?c2:0.f; c3 = v?c3:0.f;
        c4 = v?c4:0.f; c5 = v?c5:0.f; c6 = v?c6:0.f; c7 = v?c7:0.f;
      }
      _Float16 h0=(_Float16)c0, h1=(_Float16)c1, h2=(_Float16)c2, h3=(_Float16)c3;
      _Float16 h4=(_Float16)c4, h5=(_Float16)c5, h6=(_Float16)c6, h7=(_Float16)c7;
      Afh[mt][0]=h0; Afh[mt][1]=h1; Afh[mt][2]=h2; Afh[mt][3]=h3;
      Afh[mt][4]=h4; Afh[mt][5]=h5; Afh[mt][6]=h6; Afh[mt][7]=h7;
      Afl[mt][0]=(_Float16)(c0-(float)h0); Afl[mt][1]=(_Float16)(c1-(float)h1);
      Afl[mt][2]=(_Float16)(c2-(float)h2); Afl[mt][3]=(_Float16)(c3-(float)h3);
      Afl[mt][4]=(_Float16)(c4-(float)h4); Afl[mt][5]=(_Float16)(c5-(float)h5);
      Afl[mt][6]=(_Float16)(c6-(float)h6); Afl[mt][7]=(_Float16)(c7-(float)h7);
    }
    __builtin_amdgcn_sched_barrier(0);   // fence: B loads stay below A-frag build
    {
      f16x8 Bh0 = *(const f16x8*)(bph + t*16384);
      f16x8 Bl0 = *(const f16x8*)(bpl + t*16384);
      f16x8 Bh1 = *(const f16x8*)(bph + t*16384 + 512);
      f16x8 Bl1 = *(const f16x8*)(bpl + t*16384 + 512);
      #pragma unroll
      for(int mt=0;mt<MT;++mt){
        K7_MFMA3(acc[mt][0], Afh[mt], Afl[mt], Bh0, Bl0)
        K7_MFMA3(acc[mt][1], Afh[mt], Afl[mt], Bh1, Bl1)
      }
    }
    __builtin_amdgcn_sched_barrier(0);   // fence: keep pair-1 loads below pair-0
    {
      f16x8 Bh2 = *(const f16x8*)(bph + t*16384 + 1024);
      f16x8 Bl2 = *(const f16x8*)(bpl + t*16384 + 1024);
      f16x8 Bh3 = *(const f16x8*)(bph + t*16384 + 1536);
      f16x8 Bl3 = *(const f16x8*)(bpl + t*16384 + 1536);
      #pragma unroll
      for(int mt=0;mt<MT;++mt){
        K7_MFMA3(acc[mt][2], Afh[mt], Afl[mt], Bh2, Bl2)
        K7_MFMA3(acc[mt][3], Afh[mt], Afl[mt], Bh3, Bl3)
      }
    }
  }

  const float UNS = 1.f/65536.f;
  #pragma unroll
  for(int mt=0;mt<MT;++mt){
    float s[4]={0.f,0.f,0.f,0.f}, q[4]={0.f,0.f,0.f,0.f};
    #pragma unroll
    for(int jj=0;jj<4;++jj){
      int j = w*64 + jj*16 + col; float bj = sm.b1s[j];
      #pragma unroll
      for(int r=0;r<4;++r){
        float h = acc[mt][jj][r]*UNS + bj;
        s[r]+=h; q[r]+=h*h;
      }
    }
    #pragma unroll
    for(int r=0;r<4;++r){
      #pragma unroll
      for(int o=1;o<16;o<<=1){ s[r]+=__shfl_xor(s[r],o,64); q[r]+=__shfl_xor(q[r],o,64); }
    }
    if(col==0){
      #pragma unroll
      for(int r=0;r<4;++r){ int row = mt*16+quad*4+r; sm.redS[w][row]=s[r]; sm.redQ[w][row]=q[r]; }
    }
  }
  __syncthreads();
  if(tid<MT*16){
    float s=0.f,q=0.f;
    #pragma unroll
    for(int ww=0;ww<8;++ww){ s+=sm.redS[ww][tid]; q+=sm.redQ[ww][tid]; }
    float mu = s*(1.f/512.f);
    float var = q*(1.f/512.f)-mu*mu;
    sm.mu48[tid]=mu; sm.rs48[tid]=1.f/sqrtf(fmaxf(var,0.f)+1e-5f);
  }
  __syncthreads();
  float gp[4]={0.f,0.f,0.f,0.f};
  #pragma unroll
  for(int mt=0;mt<MT;++mt){
    #pragma unroll
    for(int r=0;r<4;++r){
      int lr = mt*16+quad*4+r;
      float mu=sm.mu48[lr], rs=sm.rs48[lr], wk=sm.wvS[K0+lr];
      #pragma unroll
      for(int jj=0;jj<4;++jj){
        int j = w*64 + jj*16 + col;
        float h = acc[mt][jj][r]*UNS + sm.b1s[j];
        float x = (h-mu)*rs;
        float y = x*sm.gs[j]+sm.bs[j];
        float gl = 0.5f*y*(1.f+erff(y*0.70710678118654752f));
        gp[jj] += wk*gl;
      }
    }
  }
  #pragma unroll
  for(int jj=0;jj<4;++jj){ gp[jj]+=__shfl_xor(gp[jj],16,64); gp[jj]+=__shfl_xor(gp[jj],32,64); }
  if(ln<16){
    #pragma unroll
    for(int jj=0;jj<4;++jj) sm.gfin[w*64 + jj*16 + ln] = gp[jj];
  }
  __syncthreads();
  if(tid<320){ int m=tid>>4, seg=tid&15; float p=0.f;
    for(int u=0;u<32;++u){ int j=seg*32+u; p += sm.gfin[j]*w2[m*512+j]; }
    sm.qred[m*16+seg]=p; }
  __syncthreads();
  if(tid<20){ float s=0.f;
    for(int seg=0;seg<16;++seg) s+=sm.qred[tid*16+seg];
    if(K0==0) s += b2p[tid]*wsumws[bn];         // bias term once, in half 0
    Qpws[(size_t)bn*40 + (K0?20:0) + tid]=s; }
}

__global__
__attribute__((amdgpu_flat_work_group_size(512,512)))
void k7_mlp(const float* F, const float* AO, const float* attw,
            const _Float16* w1hi, const _Float16* w1lo,
            const float* b1p, const float* lng, const float* lnb,
            const float* w2, const float* b2p,
            const float* Svws, const float* wsumws,
            float* Qpws){
  __shared__ K7Smem sm;
  int bid = blockIdx.x;
  int bn = bid>>1;
  if((bid&1)==0) k7_body<3,0 >(bn,F,AO,attw,w1hi,w1lo,b1p,lng,lnb,w2,b2p,Svws,wsumws,Qpws,sm);
  else           k7_body<2,48>(bn,F,AO,attw,w1hi,w1lo,b1p,lng,lnb,w2,b2p,Svws,wsumws,Qpws,sm);
}

// ---------------- K8: per-(b,n) top-51 mask + normalize -> out1 ----------------
__global__ __launch_bounds__(256) void k8_topk(const float* F, const float* T,
                                               const float* Qpws, float* out1){
  int bn = blockIdx.x; int tid = threadIdx.x;
  int w = tid>>6, ln = tid&63;
  __shared__ float Fv[512];
  __shared__ float QpS[20];
  __shared__ float ninv[20];
  __shared__ unsigned char selb[20][64];
  for(int e=tid;e<512;e+=256) Fv[e]=F[(size_t)bn*512+e];
  if(tid<20) QpS[tid]=Qpws[(size_t)bn*40+tid] + Qpws[(size_t)bn*40+20+tid];
  __syncthreads();
  for(int rr=0; rr<5; ++rr){
    int m = rr*4 + w;
    float qv[8]; uint key[8];
    const float4* tp = (const float4*)(T + (size_t)m*512 + ln*8);
    float4 t0 = tp[0], t1 = tp[1];
    float tf[8] = {t0.x,t0.y,t0.z,t0.w,t1.x,t1.y,t1.z,t1.w};
    float qp = QpS[m];
    #pragma unroll
    for(int i=0;i<8;++i){ float p = Fv[ln*8+i]*tf[i]; qv[i]=p*qp;
      key[i]=__float_as_uint(qv[i])&0x7fffffffu; }
    uint th=0u;
    for(int bit=30; bit>=0; --bit){
      uint cand = th | (1u<<bit);
      int c=0;
      #pragma unroll
      for(int i=0;i<8;++i) c += (key[i]>=cand);
      c = wsumi(c);
      if(c>=51) th=cand;
    }
    int cg=0;
    #pragma unroll
    for(int i=0;i<8;++i) cg += (key[i]>th);
    cg = wsumi(cg);
    int rneed = 51-cg;
    int eqc=0;
    #pragma unroll
    for(int i=0;i<8;++i) eqc += (key[i]==th);
    int pre=eqc;
    for(int o=1;o<64;o<<=1){ int v=__shfl_up(pre,o,64); if(ln>=o) pre+=v; }
    pre -= eqc;
    unsigned char mbits=0; float ss=0.f; int rk=pre;
    #pragma unroll
    for(int i=0;i<8;++i){
      bool s;
      if(key[i]>th) s=true;
      else if(key[i]==th){ s = (rk<rneed); rk++; }
      else s=false;
      if(s){ mbits |= (unsigned char)(1u<<i); ss += qv[i]*qv[i]; }
    }
    ss = wsumf(ss);
    if(ln==0) ninv[m] = 1.f/fmaxf(sqrtf(ss),1e-6f);
    selb[m][ln]=mbits;
  }
  __syncthreads();
  size_t base=(size_t)bn*10240;
  for(int e=tid;e<10240;e+=256){
    int d=e/20, mm=e-d*20;
    float val=0.f;
    if((selb[mm][d>>3]>>(d&7))&1){
      val = Fv[d]*T[(size_t)mm*512+d]*QpS[mm]*ninv[mm];
    }
    out1[base+e]=val;
  }
}

extern "C" void kernel_launch(void* const* d_in, const int* in_sizes, int n_in,
                              void* d_out, int out_size, void* d_ws, size_t ws_size,
                              hipStream_t stream){
  const float* F    = (const float*)d_in[0];
  const float* text = (const float*)d_in[1];
  const float* ipw  = (const float*)d_in[2];
  const float* ipb  = (const float*)d_in[3];
  const float* outw = (const float*)d_in[4];
  const float* outb = (const float*)d_in[5];
  const float* g1   = (const float*)d_in[6];
  const float* b1   = (const float*)d_in[7];
  const float* g2   = (const float*)d_in[8];
  const float* b2   = (const float*)d_in[9];
  const float* mw1  = (const float*)d_in[10];
  const float* mb1  = (const float*)d_in[11];
  const float* mlg  = (const float*)d_in[12];
  const float* mlb  = (const float*)d_in[13];
  const float* mw2  = (const float*)d_in[14];
  const float* mb2  = (const float*)d_in[15];
  const float* tmpl = (const float*)d_in[16];
  float* ws = (float*)d_ws;
  float* WT   = ws;
  float* OWT  = ws +  786432;
  float* qws  = ws + 1048576;
  float* kmat = ws + 1088000;
  float* vmat = ws + 1890816;
  float* attf = ws + 2693632;
  float* attw = ws + 3659520;
  float* ctx  = ws + 3780256;
  float* AO   = ws + 4095648;
  float* Qp   = ws + 4411040;
  _Float16* w1hi = (_Float16*)(ws + 4473760);
  _Float16* w1lo = (_Float16*)(ws + 4604832);
  // dead-region reuse (consumers of qws/kmat finish at k3):
  float* wsum = ws + 1048576;   // 1568 fl in old qws region
  float* Sv   = ws + 1088000;   // 802816 fl in old kmat region (exact fit)
  float* out1 = (float*)d_out;
  float* out2 = out1 + 16056320;

  hipLaunchKernelGGL(k0_transpose, dim3(2048), dim3(256), 0, stream, ipw, outw, mw1, WT, OWT, w1hi, w1lo);
  hipLaunchKernelGGL(k1_q,   dim3(154), dim3(256), 0, stream, text, ipb, g1, b1, WT, qws);
  hipLaunchKernelGGL(k2_kv,  dim3(196), dim3(512), 0, stream, F, ipb, g1, b1, WT, kmat, vmat);
  hipLaunchKernelGGL(k3_attn,dim3(640), dim3(256), 0, stream, qws, kmat, attf);
  hipLaunchKernelGGL(k4_ctx, dim3(640), dim3(256), 0, stream, attf, vmat, ctx);
  hipLaunchKernelGGL(k5_attw,dim3(472), dim3(256), 0, stream, attf, attw, out2);
  hipLaunchKernelGGL(k6_ao,  dim3(77),  dim3(512), 0, stream, ctx, OWT, outb, g2, b2, AO);
  hipLaunchKernelGGL(k6b_sv, dim3(200), dim3(512), 0, stream, AO, attw, Sv, wsum);
  hipLaunchKernelGGL(k7_mlp, dim3(3136),dim3(512), 0, stream, F, AO, attw, w1hi, w1lo, mb1, mlg, mlb, mw2, mb2, Sv, wsum, Qp);
  hipLaunchKernelGGL(k8_topk,dim3(1568),dim3(256), 0, stream, F, tmpl, Qp, out1);
}

// Round 5
// 713.911 us; speedup vs baseline: 1.3030x; 1.3030x over previous
//
#include <hip/hip_runtime.h>
#include <hip/hip_bf16.h>
#include <math.h>

// B=8 N=196 D=512 M=20 K=77 H=8 hd=64, keep=51.  All inputs/outputs fp32.
// out1 = Qs/nrm (B,N,D,M) 16,056,320 fl; out2 = attn_weights (B,K,N) 120,736 fl
// Workspace (fp32 words):
//  WT @0:786432  OWT @786432:262144  q @1048576:39424  kmat @1088000:802816
//  vmat @1890816:802816  attf @2693632:965888  attw @3659520:120736
//  ctx @3780256:315392  AO @4095648:315392  Qp @4411040:62720 (2 halves x 20/bn)
//  W1hi(fp16) @4473760: 131072 fl  W1lo(fp16) @4604832: 131072 fl -> 4735904 fl = 18.9 MB
//  Reuse after consumers finish: wsum -> qws region, Sv -> kmat region (dead after k3)
//
// R11 (post-mortem R10: per-lane A-build = uncoalesced 16-row scatter + VALU
// chain -> 549us REGRESSION, reverted. R0..R9 invariant 355-380us @ MfmaUtil
// 22.5% = the 16 per-t barrier drains (vmcnt(0)) cap duty at ~24%):
//  k7: stage ALL of A (48 rows x 512 d, hi/lo fp16 = 96KB) into LDS ONCE
//  (coalesced, one barrier), with (lane+t)&63 rotation -> bank-uniform writes
//  AND reads. t-loop = {ds_read A, global B, MFMA} with ZERO barriers and a
//  2-set register double-buffer for B (issue t+1 before consuming t).
//  LDS 111.5KB -> 1 blk/CU -> VGPR cap 256 (R0-proven mechanism).

typedef unsigned int uint;
typedef _Float16 f16x8 __attribute__((ext_vector_type(8)));
typedef float f32x4 __attribute__((ext_vector_type(4)));

#define DI __device__ __forceinline__

DI float wsumf(float v){ for(int o=32;o>0;o>>=1) v += __shfl_xor(v,o,64); return v; }
DI int   wsumi(int v){ for(int o=32;o>0;o>>=1) v += __shfl_xor(v,o,64); return v; }
DI float wmaxf(float v){ for(int o=32;o>0;o>>=1) v = fmaxf(v,__shfl_xor(v,o,64)); return v; }

// ---------------- K0: tiled transposes + W1 split/swizzle ----------------
__global__ __launch_bounds__(256) void k0_transpose(const float* ipw, const float* ow, const float* mw1,
                             float* WT, float* OWT, _Float16* w1hi, _Float16* w1lo){
  int bid = blockIdx.x;
  if(bid < 768){
    __shared__ float t[32][33];
    int tdin = bid & 15, tdout = bid >> 4;
    int tx = threadIdx.x & 31, ty = threadIdx.x >> 5;
    int dout0 = tdout*32, din0 = tdin*32;
    for(int r=ty; r<32; r+=8) t[r][tx] = ipw[(size_t)(dout0+r)*512 + din0+tx];
    __syncthreads();
    for(int r=ty; r<32; r+=8) WT[(size_t)(din0+r)*1536 + dout0+tx] = t[tx][r];
  } else if(bid < 1024){
    __shared__ float t[32][33];
    int b2 = bid - 768;
    int tdin = b2 & 15, tdout = b2 >> 4;
    int tx = threadIdx.x & 31, ty = threadIdx.x >> 5;
    int dout0 = tdout*32, din0 = tdin*32;
    for(int r=ty; r<32; r+=8) t[r][tx] = ow[(size_t)(dout0+r)*512 + din0+tx];
    __syncthreads();
    for(int r=ty; r<32; r+=8) OWT[(size_t)(din0+r)*512 + dout0+tx] = t[tx][r];
  } else {
    int i3 = (bid-1024)*256 + threadIdx.x;
    int t = i3&7, ln = (i3>>3)&63, J = (i3>>9)&31, T = i3>>14;
    int j = J*16 + (ln&15);
    int d = T*32 + ((ln>>4)<<3) + t;
    float w = mw1[j*512 + d] * 64.0f;
    _Float16 hi = (_Float16)w;
    _Float16 lo = (_Float16)(w - (float)hi);
    w1hi[i3] = hi; w1lo[i3] = lo;
  }
}

// ---------------- K1: q = LN(text) @ Wq^T + bq  (154 blocks: k x half) ----------------
__global__ __launch_bounds__(256) void k1_q(const float* text, const float* ipb,
                                            const float* g1, const float* b1p,
                                            const float* WT, float* qws){
  int k = blockIdx.x >> 1, half = blockIdx.x & 1;
  int tid = threadIdx.x;
  __shared__ float xln[512];
  __shared__ float rA[4], rB[4];
  float x0 = text[k*512+tid], x1 = text[k*512+256+tid];
  float s1 = wsumf(x0+x1), s2 = wsumf(x0*x0+x1*x1);
  int w = tid>>6, ln = tid&63;
  if(!ln){ rA[w]=s1; rB[w]=s2; }
  __syncthreads();
  float mu = (rA[0]+rA[1]+rA[2]+rA[3])*(1.f/512.f);
  float var = (rB[0]+rB[1]+rB[2]+rB[3])*(1.f/512.f) - mu*mu;
  float rs = 1.f/sqrtf(fmaxf(var,0.f) + 1e-5f);
  xln[tid]     = (x0-mu)*rs*g1[tid]     + b1p[tid];
  xln[tid+256] = (x1-mu)*rs*g1[tid+256] + b1p[tid+256];
  __syncthreads();
  int d = half*256 + tid;
  float a0=0.f,a1=0.f,a2=0.f,a3=0.f;   // 4 independent chains for ILP
  for(int din=0; din<512; din+=4){
    a0 += xln[din  ] * WT[(din  )*1536 + d];
    a1 += xln[din+1] * WT[(din+1)*1536 + d];
    a2 += xln[din+2] * WT[(din+2)*1536 + d];
    a3 += xln[din+3] * WT[(din+3)*1536 + d];
  }
  qws[k*512+d] = ipb[d] + ((a0+a1)+(a2+a3));
}

// ---------------- K2: k = LN(F)@Wk^T+bk, v = F@Wv^T+bv  (512 thr) ----------------
__global__ __launch_bounds__(512) void k2_kv(const float* F, const float* ipb,
                                             const float* g1, const float* b1p,
                                             const float* WT, float* kmat, float* vmat){
  int r0 = blockIdx.x*8; int tid = threadIdx.x;
  __shared__ float xs[8][512];
  __shared__ float xl[8][512];
  __shared__ float red[8][64];
  __shared__ float mu8[8], rs8[8];
  for(int e=tid; e<4096; e+=512){ int r=e>>9, d=e&511; xs[r][d] = F[(size_t)(r0+r)*512 + d]; }
  __syncthreads();
  {
    int r = tid>>6, t = tid&63; float s=0.f, q=0.f;
    for(int i=0;i<8;++i){ float v = xs[r][t+64*i]; s+=v; q+=v*v; }
    red[r][t] = s; __syncthreads();
    if(tid<8){ float ss=0; for(int i=0;i<64;++i) ss+=red[tid][i]; mu8[tid]=ss*(1.f/512.f); }
    __syncthreads();
    red[r][t] = q; __syncthreads();
    if(tid<8){ float qq=0; for(int i=0;i<64;++i) qq+=red[tid][i];
      float m=mu8[tid]; rs8[tid]=1.f/sqrtf(fmaxf(qq*(1.f/512.f)-m*m,0.f)+1e-5f); }
    __syncthreads();
  }
  for(int e=tid; e<4096; e+=512){ int r=e>>9, d=e&511;
    xl[r][d] = (xs[r][d]-mu8[r])*rs8[r]*g1[d] + b1p[d]; }
  __syncthreads();
  int d=tid;
  float ak[8], av[8];
  float bk=ipb[512+d], bv=ipb[1024+d];
  #pragma unroll
  for(int r=0;r<8;++r){ ak[r]=bk; av[r]=bv; }
  for(int din=0; din<512; din+=4){
    float wk[4], wv[4];
    #pragma unroll
    for(int u=0;u<4;++u){ wk[u]=WT[(din+u)*1536+512+d]; wv[u]=WT[(din+u)*1536+1024+d]; }
    #pragma unroll
    for(int r=0;r<8;++r){
      float4 a4 = *(const float4*)&xl[r][din];
      float4 x4 = *(const float4*)&xs[r][din];
      ak[r] += a4.x*wk[0]+a4.y*wk[1]+a4.z*wk[2]+a4.w*wk[3];
      av[r] += x4.x*wv[0]+x4.y*wv[1]+x4.z*wv[2]+x4.w*wv[3];
    }
  }
  #pragma unroll
  for(int r=0;r<8;++r){
    size_t base = (size_t)(r0+r)*512;
    kmat[base+d]=ak[r]; vmat[base+d]=av[r];
  }
}

// ---------------- K3: scores + softmax (640 blocks: kc x b x h) ----------------
__global__ __launch_bounds__(256) void k3_attn(const float* qws, const float* kmat, float* attf){
  int bid = blockIdx.x;
  int kc = bid>>6, b = (bid>>3)&7, h = bid&7;
  int tid = threadIdx.x; int n = tid; int w = tid>>6, ln = tid&63;
  __shared__ float qb[8][64];
  __shared__ float rM[8][4], rS[8][4];
  float4 kr[16];
  if(n < 196){
    const float4* kp = (const float4*)(kmat + ((size_t)(b*196+n))*512 + h*64);
    #pragma unroll
    for(int j=0;j<16;++j) kr[j] = kp[j];
  }
  int kbase = kc*8;
  for(int e=tid; e<512; e+=256){ int kk=e>>6, j=e&63; int k=kbase+kk;
    qb[kk][j] = (k<77)? qws[k*512 + h*64 + j] : 0.f; }
  __syncthreads();
  float sc[8];
  #pragma unroll
  for(int kk=0;kk<8;++kk){
    float s = 0.f;
    if(n<196){
      const float4* q4 = (const float4*)qb[kk];
      #pragma unroll
      for(int j=0;j<16;++j){ float4 q = q4[j];
        s += q.x*kr[j].x + q.y*kr[j].y + q.z*kr[j].z + q.w*kr[j].w; }
      sc[kk] = s*0.125f;
    } else sc[kk] = -INFINITY;
  }
  #pragma unroll
  for(int kk=0;kk<8;++kk){ float m = wmaxf(sc[kk]); if(!ln) rM[kk][w]=m; }
  __syncthreads();
  float ex[8];
  #pragma unroll
  for(int kk=0;kk<8;++kk){
    float m = fmaxf(fmaxf(rM[kk][0],rM[kk][1]),fmaxf(rM[kk][2],rM[kk][3]));
    float e = expf(sc[kk]-m);
    ex[kk]=e;
    float s = wsumf(e); if(!ln) rS[kk][w]=s;
  }
  __syncthreads();
  #pragma unroll
  for(int kk=0;kk<8;++kk){
    int k = kbase+kk;
    if(k<77 && n<196){
      float tot = rS[kk][0]+rS[kk][1]+rS[kk][2]+rS[kk][3];
      attf[(((size_t)(b*8+h))*77 + k)*196 + n] = ex[kk]/tot;
    }
  }
}

// ---------------- K4: ctx = attn @ v (640 blocks: kc x b x h) ----------------
__global__ __launch_bounds__(256) void k4_ctx(const float* attf, const float* vmat, float* ctx){
  int bid = blockIdx.x;
  int kc = bid>>6, b = (bid>>3)&7, h = bid&7;
  int tid = threadIdx.x; int ng = tid>>6, j = tid&63;
  __shared__ float vT[196][64];
  __shared__ float aT[8][196];
  __shared__ float red[8][4][64];
  for(int e=tid; e<196*16; e+=256){ int n=e>>4, jc=e&15;
    const float4* vp = (const float4*)(vmat + ((size_t)(b*196+n))*512 + h*64);
    *(float4*)&vT[n][jc*4] = vp[jc];
  }
  int kbase=kc*8;
  for(int e=tid; e<8*196; e+=256){ int kk=e/196, n=e-kk*196; int k=kbase+kk;
    aT[kk][n] = (k<77)? attf[(((size_t)(b*8+h))*77+k)*196+n] : 0.f; }
  __syncthreads();
  float vr[49];
  #pragma unroll
  for(int t=0;t<49;++t) vr[t] = vT[ng*49+t][j];
  #pragma unroll
  for(int kk=0;kk<8;++kk){
    float p=0.f;
    #pragma unroll
    for(int t=0;t<49;++t) p += aT[kk][ng*49+t]*vr[t];
    red[kk][ng][j]=p;
  }
  __syncthreads();
  for(int e=tid; e<512; e+=256){ int kk=e>>6, j2=e&63; int k=kbase+kk;
    if(k<77){
      float s = red[kk][0][j2]+red[kk][1][j2]+red[kk][2][j2]+red[kk][3][j2];
      ctx[((size_t)(b*77+k))*512 + h*64 + j2] = s;
    } }
}

// ---------------- K5: attn_weights = mean over H ----------------
__global__ void k5_attw(const float* attf, float* attw, float* out2){
  int idx = blockIdx.x*256+threadIdx.x;
  if(idx >= 8*77*196) return;
  int b = idx / (77*196); int rem = idx - b*(77*196);
  float s=0.f;
  #pragma unroll
  for(int h=0;h<8;++h) s += attf[((size_t)(b*8+h))*77*196 + rem];
  s *= 0.125f;
  attw[idx]=s; out2[idx]=s;
}

// ---------------- K6: AO = LN2(ctx @ out_w^T + out_b)  (512 thr) ----------------
__global__ __launch_bounds__(512) void k6_ao(const float* ctx, const float* OWT,
                                             const float* ob, const float* g2, const float* b2p,
                                             float* AO){
  int R0 = blockIdx.x*8; int tid = threadIdx.x;
  __shared__ float xs[8][512];
  __shared__ float ao[8][512];
  __shared__ float red[8][64];
  __shared__ float mu8[8], rs8[8];
  for(int e=tid;e<4096;e+=512){ int r=e>>9,d=e&511; xs[r][d]=ctx[(size_t)(R0+r)*512+d]; }
  __syncthreads();
  int d=tid;
  float a[8]; float obv=ob[d];
  #pragma unroll
  for(int r=0;r<8;++r) a[r]=obv;
  for(int din=0;din<512;din+=4){
    float wv[4];
    #pragma unroll
    for(int u=0;u<4;++u) wv[u]=OWT[(din+u)*512+d];
    #pragma unroll
    for(int r=0;r<8;++r){
      float4 x4 = *(const float4*)&xs[r][din];
      a[r] += x4.x*wv[0]+x4.y*wv[1]+x4.z*wv[2]+x4.w*wv[3];
    }
  }
  #pragma unroll
  for(int r=0;r<8;++r) ao[r][d]=a[r];
  __syncthreads();
  {
    int r=tid>>6,t=tid&63; float s=0.f,q=0.f;
    for(int i=0;i<8;++i){ float v=ao[r][t+64*i]; s+=v; q+=v*v; }
    red[r][t]=s; __syncthreads();
    if(tid<8){ float ss=0; for(int i=0;i<64;++i) ss+=red[tid][i]; mu8[tid]=ss*(1.f/512.f); }
    __syncthreads(); red[r][t]=q; __syncthreads();
    if(tid<8){ float qq=0; for(int i=0;i<64;++i) qq+=red[tid][i];
      float m=mu8[tid]; rs8[tid]=1.f/sqrtf(fmaxf(qq*(1.f/512.f)-m*m,0.f)+1e-5f); }
    __syncthreads();
  }
  for(int e=tid;e<4096;e+=512){ int r=e>>9,dd=e&511;
    AO[(size_t)(R0+r)*512+dd] = (ao[r][dd]-mu8[r])*rs8[r]*g2[dd] + b2p[dd]; }
}

// ---------------- K6b: Sv = (1/77) attw^T @ AO per (b, 8-n tile); wsum ---------
__global__ __launch_bounds__(512) void k6b_sv(const float* AO, const float* attw,
                                              float* Svws, float* wsumws){
  int bid = blockIdx.x;
  int b = bid/25, nt = bid - b*25;
  int n0 = nt*8;
  int tid = threadIdx.x;
  __shared__ float wsK[80][8];
  for(int e=tid; e<640; e+=512){ int k=e>>3, r=e&7; int n=n0+r;
    wsK[k][r] = (k<77 && n<196)? attw[((size_t)(b*77+k))*196 + n] : 0.f; }
  __syncthreads();
  if(tid<8){ int n=n0+tid;
    if(n<196){ float s=0.f;
      for(int k=0;k<77;++k) s+=wsK[k][tid];
      wsumws[b*196+n]=s; } }
  int d = tid;
  float acc[8];
  #pragma unroll
  for(int r=0;r<8;++r) acc[r]=0.f;
  const float* aob = AO + (size_t)b*77*512 + d;
  for(int k=0;k<77;++k){
    float a = aob[(size_t)k*512];
    #pragma unroll
    for(int r=0;r<8;++r) acc[r] += wsK[k][r]*a;
  }
  #pragma unroll
  for(int r=0;r<8;++r){ int n=n0+r; if(n<196)
    Svws[((size_t)(b*196+n))*512 + d] = acc[r]*(1.f/77.f); }
}

// ---------------- K7: per-(b,n,half) fused MLP; A fully LDS-resident, barrier-free t-loop
// Row-split: half 0 = rows 0..47 (MT=3), half 1 = rows 48..79 (MT=2).
// Stage: clean(hi/lo fp16) for all MT*16 rows x 512 d -> LDS once (coalesced
// AO/F/Sv reads; (lane+t)&63 rotation = bank-uniform writes AND reads).
// t-loop: ds_read A + global B (2-set register dbuf, issue t+1 before use t)
// + MFMA. ZERO barriers. LDS 111.5KB -> 1 blk/CU -> VGPR cap 256 (R0-proven).
struct __align__(16) K7Smem {
  _Float16 Ah[3*16*512];    // [mt][t][pos 0..63][8], pos=(lane+t)&63
  _Float16 Al[3*16*512];
  float b1s[512], gs[512], bs[512];
  float wvS[80];
  float redS[8][48], redQ[8][48];
  float mu48[48], rs48[48];
  float gfin[512];
  float qred[320];
};   // 111.5 KB total

#define K7_MFMA3(ACC, AFH, AFL, BH, BL) \
  ACC = __builtin_amdgcn_mfma_f32_16x16x32_f16(AFL, BH, ACC, 0,0,0); \
  ACC = __builtin_amdgcn_mfma_f32_16x16x32_f16(AFH, BL, ACC, 0,0,0); \
  ACC = __builtin_amdgcn_mfma_f32_16x16x32_f16(AFH, BH, ACC, 0,0,0);

struct Bset { f16x8 h0,h1,h2,h3,l0,l1,l2,l3; };

DI void loadB(Bset& s, const _Float16* bph, const _Float16* bpl, int t){
  const _Float16* ph = bph + t*16384;
  const _Float16* pl = bpl + t*16384;
  s.h0 = *(const f16x8*)(ph);       s.h1 = *(const f16x8*)(ph+512);
  s.h2 = *(const f16x8*)(ph+1024);  s.h3 = *(const f16x8*)(ph+1536);
  s.l0 = *(const f16x8*)(pl);       s.l1 = *(const f16x8*)(pl+512);
  s.l2 = *(const f16x8*)(pl+1024);  s.l3 = *(const f16x8*)(pl+1536);
}

template<int MT>
DI void stepMFMA(f32x4 acc[][4], const _Float16* Ah, const _Float16* Al,
                 const Bset& B, int t, int ln){
  #pragma unroll
  for(int mt=0; mt<MT; ++mt){
    int off = (mt*16 + t)*512 + ((ln + t)&63)*8;
    f16x8 fh = *(const f16x8*)&Ah[off];
    f16x8 fl = *(const f16x8*)&Al[off];
    K7_MFMA3(acc[mt][0], fh, fl, B.h0, B.l0)
    K7_MFMA3(acc[mt][1], fh, fl, B.h1, B.l1)
    K7_MFMA3(acc[mt][2], fh, fl, B.h2, B.l2)
    K7_MFMA3(acc[mt][3], fh, fl, B.h3, B.l3)
  }
}

template<int MT, int K0>
DI void k7_body(int bn, const float* F, const float* AO, const float* attw,
                const _Float16* w1hi, const _Float16* w1lo,
                const float* b1p, const float* lng, const float* lnb,
                const float* w2, const float* b2p,
                const float* Svws, const float* wsumws,
                float* Qpws, K7Smem& sm){
  int b = bn/196, n = bn - b*196;
  int tid = threadIdx.x; int w = tid>>6, ln = tid&63;
  int col = ln&15, quad = ln>>4;
  const float* AObase = AO + (size_t)b*77*512;
  sm.b1s[tid] = b1p[tid]; sm.gs[tid] = lng[tid]; sm.bs[tid] = lnb[tid];
  if(tid<80) sm.wvS[tid] = (tid<77)? attw[((size_t)(b*77+tid))*196+n] : 0.f;
  __syncthreads();

  // ---- stage clean (hi/lo) for MT*16 rows into LDS; this thread owns fixed d0
  {
    int d0 = (tid&63)*8;            // fixed k-slice for this thread
    int r0 = tid>>6;                // base row 0..7 (it adds 8 per step)
    int t  = d0>>5;
    int k8 = (d0&31)>>3;
    float4 f0 = *(const float4*)&F[(size_t)bn*512 + d0];
    float4 f1 = *(const float4*)&F[(size_t)bn*512 + d0+4];
    float4 sv0 = *(const float4*)&Svws[(size_t)bn*512 + d0];
    float4 sv1 = *(const float4*)&Svws[(size_t)bn*512 + d0+4];
    float fk[8] = {f0.x*1024.f,f0.y*1024.f,f0.z*1024.f,f0.w*1024.f,
                   f1.x*1024.f,f1.y*1024.f,f1.z*1024.f,f1.w*1024.f};
    float sv[8] = {sv0.x,sv0.y,sv0.z,sv0.w,sv1.x,sv1.y,sv1.z,sv1.w};
    #pragma unroll
    for(int it=0; it<MT*2; ++it){
      int row = r0 + it*8;          // local row 0..MT*16-1
      int grow = K0 + row;
      bool ok = grow < 77;
      int rl = ok ? grow : 0;
      float wm = ok ? sm.wvS[grow] : 0.f;
      const float* ap = AObase + (size_t)rl*512 + d0;
      float4 a0 = *(const float4*)ap;
      float4 a1 = *(const float4*)(ap+4);
      float av[8] = {a0.x,a0.y,a0.z,a0.w,a1.x,a1.y,a1.z,a1.w};
      f16x8 hfrag, lfrag;
      #pragma unroll
      for(int i=0;i<8;++i){
        float c = ok ? fk[i]*(wm*av[i] - sv[i]) : 0.f;
        _Float16 h = (_Float16)c;
        hfrag[i] = h;
        lfrag[i] = (_Float16)(c - (float)h);
      }
      int lane = (row&15) | (k8<<4);
      int pos = (lane + t)&63;
      int idx = (((row>>4)*16 + t)*512) + pos*8;
      *(f16x8*)&sm.Ah[idx] = hfrag;
      *(f16x8*)&sm.Al[idx] = lfrag;
    }
  }
  __syncthreads();
  // ---- barrier-free t-loop: A from LDS, B double-buffered from global ----
  f32x4 acc[MT][4];
  #pragma unroll
  for(int mt=0;mt<MT;++mt)
    #pragma unroll
    for(int jj=0;jj<4;++jj) acc[mt][jj] = (f32x4){0.f,0.f,0.f,0.f};

  const _Float16* bph = w1hi + ((w*4)*64 + ln)*8;  // +512 per jj, +16384 per t
  const _Float16* bpl = w1lo + ((w*4)*64 + ln)*8;

  Bset s0, s1;
  loadB(s0, bph, bpl, 0);
  #pragma unroll 1
  for(int tt=0; tt<16; tt+=2){
    loadB(s1, bph, bpl, tt+1);                 // prefetch odd step
    stepMFMA<MT>(acc, sm.Ah, sm.Al, s0, tt, ln);
    if(tt+2<16) loadB(s0, bph, bpl, tt+2);     // prefetch next even step
    stepMFMA<MT>(acc, sm.Ah, sm.Al, s1, tt+1, ln);
  }

  const float UNS = 1.f/65536.f;
  #pragma unroll
  for(int mt=0;mt<MT;++mt){
    float s[4]={0.f,0.f,0.f,0.f}, q[4]={0.f,0.f,0.f,0.f};
    #pragma unroll
    for(int jj=0;jj<4;++jj){
      int j = w*64 + jj*16 + col; float bj = sm.b1s[j];
      #pragma unroll
      for(int r=0;r<4;++r){
        float h = acc[mt][jj][r]*UNS + bj;
        s[r]+=h; q[r]+=h*h;
      }
    }
    #pragma unroll
    for(int r=0;r<4;++r){
      #pragma unroll
      for(int o=1;o<16;o<<=1){ s[r]+=__shfl_xor(s[r],o,64); q[r]+=__shfl_xor(q[r],o,64); }
    }
    if(col==0){
      #pragma unroll
      for(int r=0;r<4;++r){ int row = mt*16+quad*4+r; sm.redS[w][row]=s[r]; sm.redQ[w][row]=q[r]; }
    }
  }
  __syncthreads();
  if(tid<MT*16){
    float s=0.f,q=0.f;
    #pragma unroll
    for(int ww=0;ww<8;++ww){ s+=sm.redS[ww][tid]; q+=sm.redQ[ww][tid]; }
    float mu = s*(1.f/512.f);
    float var = q*(1.f/512.f)-mu*mu;
    sm.mu48[tid]=mu; sm.rs48[tid]=1.f/sqrtf(fmaxf(var,0.f)+1e-5f);
  }
  __syncthreads();
  float gp[4]={0.f,0.f,0.f,0.f};
  #pragma unroll
  for(int mt=0;mt<MT;++mt){
    #pragma unroll
    for(int r=0;r<4;++r){
      int lr = mt*16+quad*4+r;
      float mu=sm.mu48[lr], rs=sm.rs48[lr], wk=sm.wvS[K0+lr];
      #pragma unroll
      for(int jj=0;jj<4;++jj){
        int j = w*64 + jj*16 + col;
        float h = acc[mt][jj][r]*UNS + sm.b1s[j];
        float x = (h-mu)*rs;
        float y = x*sm.gs[j]+sm.bs[j];
        float gl = 0.5f*y*(1.f+erff(y*0.70710678118654752f));
        gp[jj] += wk*gl;
      }
    }
  }
  #pragma unroll
  for(int jj=0;jj<4;++jj){ gp[jj]+=__shfl_xor(gp[jj],16,64); gp[jj]+=__shfl_xor(gp[jj],32,64); }
  if(ln<16){
    #pragma unroll
    for(int jj=0;jj<4;++jj) sm.gfin[w*64 + jj*16 + ln] = gp[jj];
  }
  __syncthreads();
  if(tid<320){ int m=tid>>4, seg=tid&15; float p=0.f;
    for(int u=0;u<32;++u){ int j=seg*32+u; p += sm.gfin[j]*w2[m*512+j]; }
    sm.qred[m*16+seg]=p; }
  __syncthreads();
  if(tid<20){ float s=0.f;
    for(int seg=0;seg<16;++seg) s+=sm.qred[tid*16+seg];
    if(K0==0) s += b2p[tid]*wsumws[bn];         // bias term once, in half 0
    Qpws[(size_t)bn*40 + (K0?20:0) + tid]=s; }
}

__global__
__attribute__((amdgpu_flat_work_group_size(512,512)))
void k7_mlp(const float* F, const float* AO, const float* attw,
            const _Float16* w1hi, const _Float16* w1lo,
            const float* b1p, const float* lng, const float* lnb,
            const float* w2, const float* b2p,
            const float* Svws, const float* wsumws,
            float* Qpws){
  __shared__ K7Smem sm;
  int bid = blockIdx.x;
  int bn = bid>>1;
  if((bid&1)==0) k7_body<3,0 >(bn,F,AO,attw,w1hi,w1lo,b1p,lng,lnb,w2,b2p,Svws,wsumws,Qpws,sm);
  else           k7_body<2,48>(bn,F,AO,attw,w1hi,w1lo,b1p,lng,lnb,w2,b2p,Svws,wsumws,Qpws,sm);
}

// ---------------- K8: per-(b,n) top-51 mask + normalize -> out1 ----------------
__global__ __launch_bounds__(256) void k8_topk(const float* F, const float* T,
                                               const float* Qpws, float* out1){
  int bn = blockIdx.x; int tid = threadIdx.x;
  int w = tid>>6, ln = tid&63;
  __shared__ float Fv[512];
  __shared__ float QpS[20];
  __shared__ float ninv[20];
  __shared__ unsigned char selb[20][64];
  for(int e=tid;e<512;e+=256) Fv[e]=F[(size_t)bn*512+e];
  if(tid<20) QpS[tid]=Qpws[(size_t)bn*40+tid] + Qpws[(size_t)bn*40+20+tid];
  __syncthreads();
  for(int rr=0; rr<5; ++rr){
    int m = rr*4 + w;
    float qv[8]; uint key[8];
    const float4* tp = (const float4*)(T + (size_t)m*512 + ln*8);
    float4 t0 = tp[0], t1 = tp[1];
    float tf[8] = {t0.x,t0.y,t0.z,t0.w,t1.x,t1.y,t1.z,t1.w};
    float qp = QpS[m];
    #pragma unroll
    for(int i=0;i<8;++i){ float p = Fv[ln*8+i]*tf[i]; qv[i]=p*qp;
      key[i]=__float_as_uint(qv[i])&0x7fffffffu; }
    uint th=0u;
    for(int bit=30; bit>=0; --bit){
      uint cand = th | (1u<<bit);
      int c=0;
      #pragma unroll
      for(int i=0;i<8;++i) c += (key[i]>=cand);
      c = wsumi(c);
      if(c>=51) th=cand;
    }
    int cg=0;
    #pragma unroll
    for(int i=0;i<8;++i) cg += (key[i]>th);
    cg = wsumi(cg);
    int rneed = 51-cg;
    int eqc=0;
    #pragma unroll
    for(int i=0;i<8;++i) eqc += (key[i]==th);
    int pre=eqc;
    for(int o=1;o<64;o<<=1){ int v=__shfl_up(pre,o,64); if(ln>=o) pre+=v; }
    pre -= eqc;
    unsigned char mbits=0; float ss=0.f; int rk=pre;
    #pragma unroll
    for(int i=0;i<8;++i){
      bool s;
      if(key[i]>th) s=true;
      else if(key[i]==th){ s = (rk<rneed); rk++; }
      else s=false;
      if(s){ mbits |= (unsigned char)(1u<<i); ss += qv[i]*qv[i]; }
    }
    ss = wsumf(ss);
    if(ln==0) ninv[m] = 1.f/fmaxf(sqrtf(ss),1e-6f);
    selb[m][ln]=mbits;
  }
  __syncthreads();
  size_t base=(size_t)bn*10240;
  for(int e=tid;e<10240;e+=256){
    int d=e/20, mm=e-d*20;
    float val=0.f;
    if((selb[mm][d>>3]>>(d&7))&1){
      val = Fv[d]*T[(size_t)mm*512+d]*QpS[mm]*ninv[mm];
    }
    out1[base+e]=val;
  }
}

extern "C" void kernel_launch(void* const* d_in, const int* in_sizes, int n_in,
                              void* d_out, int out_size, void* d_ws, size_t ws_size,
                              hipStream_t stream){
  const float* F    = (const float*)d_in[0];
  const float* text = (const float*)d_in[1];
  const float* ipw  = (const float*)d_in[2];
  const float* ipb  = (const float*)d_in[3];
  const float* outw = (const float*)d_in[4];
  const float* outb = (const float*)d_in[5];
  const float* g1   = (const float*)d_in[6];
  const float* b1   = (const float*)d_in[7];
  const float* g2   = (const float*)d_in[8];
  const float* b2   = (const float*)d_in[9];
  const float* mw1  = (const float*)d_in[10];
  const float* mb1  = (const float*)d_in[11];
  const float* mlg  = (const float*)d_in[12];
  const float* mlb  = (const float*)d_in[13];
  const float* mw2  = (const float*)d_in[14];
  const float* mb2  = (const float*)d_in[15];
  const float* tmpl = (const float*)d_in[16];
  float* ws = (float*)d_ws;
  float* WT   = ws;
  float* OWT  = ws +  786432;
  float* qws  = ws + 1048576;
  float* kmat = ws + 1088000;
  float* vmat = ws + 1890816;
  float* attf = ws + 2693632;
  float* attw = ws + 3659520;
  float* ctx  = ws + 3780256;
  float* AO   = ws + 4095648;
  float* Qp   = ws + 4411040;
  _Float16* w1hi = (_Float16*)(ws + 4473760);
  _Float16* w1lo = (_Float16*)(ws + 4604832);
  // dead-region reuse (consumers of qws/kmat finish at k3):
  float* wsum = ws + 1048576;   // 1568 fl in old qws region
  float* Sv   = ws + 1088000;   // 802816 fl in old kmat region (exact fit)
  float* out1 = (float*)d_out;
  float* out2 = out1 + 16056320;

  hipLaunchKernelGGL(k0_transpose, dim3(2048), dim3(256), 0, stream, ipw, outw, mw1, WT, OWT, w1hi, w1lo);
  hipLaunchKernelGGL(k1_q,   dim3(154), dim3(256), 0, stream, text, ipb, g1, b1, WT, qws);
  hipLaunchKernelGGL(k2_kv,  dim3(196), dim3(512), 0, stream, F, ipb, g1, b1, WT, kmat, vmat);
  hipLaunchKernelGGL(k3_attn,dim3(640), dim3(256), 0, stream, qws, kmat, attf);
  hipLaunchKernelGGL(k4_ctx, dim3(640), dim3(256), 0, stream, attf, vmat, ctx);
  hipLaunchKernelGGL(k5_attw,dim3(472), dim3(256), 0, stream, attf, attw, out2);
  hipLaunchKernelGGL(k6_ao,  dim3(77),  dim3(512), 0, stream, ctx, OWT, outb, g2, b2, AO);
  hipLaunchKernelGGL(k6b_sv, dim3(200), dim3(512), 0, stream, AO, attw, Sv, wsum);
  hipLaunchKernelGGL(k7_mlp, dim3(3136),dim3(512), 0, stream, F, AO, attw, w1hi, w1lo, mb1, mlg, mlb, mw2, mb2, Sv, wsum, Qp);
  hipLaunchKernelGGL(k8_topk,dim3(1568),dim3(256), 0, stream, F, tmpl, Qp, out1);
}

// Round 6
// 688.132 us; speedup vs baseline: 1.3518x; 1.0375x over previous
//
#include <hip/hip_runtime.h>
#include <hip/hip_bf16.h>
#include <math.h>

// B=8 N=196 D=512 M=20 K=77 H=8 hd=64, keep=51.  All inputs/outputs fp32.
// out1 = Qs/nrm (B,N,D,M) 16,056,320 fl; out2 = attn_weights (B,K,N) 120,736 fl
// Workspace (fp32 words):
//  WT @0:786432  OWT @786432:262144  q @1048576:39424  kmat @1088000:802816
//  vmat @1890816:802816  attf @2693632:965888  attw @3659520:120736
//  ctx @3780256:315392  AO @4095648:315392  (Qp region unused)
//  W1hi(fp16) @4473760: 131072 fl  W1lo(fp16) @4604832: 131072 fl
//  Dead-region reuse: wsum -> qws (@1048576, dead after k3)
//                     Sv   -> kmat (@1088000, dead after k3)
//                     Qp   -> OWT  (@786432, 94080 fl needed, dead after k6)
//
// R12 (from R11 counters: k7 305us, MfmaUtil 29, VALU 29, Occ 20%, no spill,
// L2 B-traffic only 31% of ceiling -> latency-bound at 1 blk/CU, phases
// serialize with no second block to overlap):
//  3-way row split (32+32+16 rows, MT=2/2/1) -> A-LDS 64KB, struct 77.6KB
//  <= 80KB -> 2 blocks/CU -> 16 waves/CU -> VGPR cap 128 (proven mechanism),
//  full hi/lo precision kept, barrier-free t-loop kept. Qp = 3 partials/bn
//  in old OWT region; k8 sums 3. Cost: B re-read x1.5 (still << L2 ceiling).

typedef unsigned int uint;
typedef _Float16 f16x8 __attribute__((ext_vector_type(8)));
typedef float f32x4 __attribute__((ext_vector_type(4)));

#define DI __device__ __forceinline__

DI float wsumf(float v){ for(int o=32;o>0;o>>=1) v += __shfl_xor(v,o,64); return v; }
DI int   wsumi(int v){ for(int o=32;o>0;o>>=1) v += __shfl_xor(v,o,64); return v; }
DI float wmaxf(float v){ for(int o=32;o>0;o>>=1) v = fmaxf(v,__shfl_xor(v,o,64)); return v; }

// ---------------- K0: tiled transposes + W1 split/swizzle ----------------
__global__ __launch_bounds__(256) void k0_transpose(const float* ipw, const float* ow, const float* mw1,
                             float* WT, float* OWT, _Float16* w1hi, _Float16* w1lo){
  int bid = blockIdx.x;
  if(bid < 768){
    __shared__ float t[32][33];
    int tdin = bid & 15, tdout = bid >> 4;
    int tx = threadIdx.x & 31, ty = threadIdx.x >> 5;
    int dout0 = tdout*32, din0 = tdin*32;
    for(int r=ty; r<32; r+=8) t[r][tx] = ipw[(size_t)(dout0+r)*512 + din0+tx];
    __syncthreads();
    for(int r=ty; r<32; r+=8) WT[(size_t)(din0+r)*1536 + dout0+tx] = t[tx][r];
  } else if(bid < 1024){
    __shared__ float t[32][33];
    int b2 = bid - 768;
    int tdin = b2 & 15, tdout = b2 >> 4;
    int tx = threadIdx.x & 31, ty = threadIdx.x >> 5;
    int dout0 = tdout*32, din0 = tdin*32;
    for(int r=ty; r<32; r+=8) t[r][tx] = ow[(size_t)(dout0+r)*512 + din0+tx];
    __syncthreads();
    for(int r=ty; r<32; r+=8) OWT[(size_t)(din0+r)*512 + dout0+tx] = t[tx][r];
  } else {
    int i3 = (bid-1024)*256 + threadIdx.x;
    int t = i3&7, ln = (i3>>3)&63, J = (i3>>9)&31, T = i3>>14;
    int j = J*16 + (ln&15);
    int d = T*32 + ((ln>>4)<<3) + t;
    float w = mw1[j*512 + d] * 64.0f;
    _Float16 hi = (_Float16)w;
    _Float16 lo = (_Float16)(w - (float)hi);
    w1hi[i3] = hi; w1lo[i3] = lo;
  }
}

// ---------------- K1: q = LN(text) @ Wq^T + bq  (154 blocks: k x half) ----------------
__global__ __launch_bounds__(256) void k1_q(const float* text, const float* ipb,
                                            const float* g1, const float* b1p,
                                            const float* WT, float* qws){
  int k = blockIdx.x >> 1, half = blockIdx.x & 1;
  int tid = threadIdx.x;
  __shared__ float xln[512];
  __shared__ float rA[4], rB[4];
  float x0 = text[k*512+tid], x1 = text[k*512+256+tid];
  float s1 = wsumf(x0+x1), s2 = wsumf(x0*x0+x1*x1);
  int w = tid>>6, ln = tid&63;
  if(!ln){ rA[w]=s1; rB[w]=s2; }
  __syncthreads();
  float mu = (rA[0]+rA[1]+rA[2]+rA[3])*(1.f/512.f);
  float var = (rB[0]+rB[1]+rB[2]+rB[3])*(1.f/512.f) - mu*mu;
  float rs = 1.f/sqrtf(fmaxf(var,0.f) + 1e-5f);
  xln[tid]     = (x0-mu)*rs*g1[tid]     + b1p[tid];
  xln[tid+256] = (x1-mu)*rs*g1[tid+256] + b1p[tid+256];
  __syncthreads();
  int d = half*256 + tid;
  float a0=0.f,a1=0.f,a2=0.f,a3=0.f;   // 4 independent chains for ILP
  for(int din=0; din<512; din+=4){
    a0 += xln[din  ] * WT[(din  )*1536 + d];
    a1 += xln[din+1] * WT[(din+1)*1536 + d];
    a2 += xln[din+2] * WT[(din+2)*1536 + d];
    a3 += xln[din+3] * WT[(din+3)*1536 + d];
  }
  qws[k*512+d] = ipb[d] + ((a0+a1)+(a2+a3));
}

// ---------------- K2: k = LN(F)@Wk^T+bk, v = F@Wv^T+bv  (512 thr) ----------------
__global__ __launch_bounds__(512) void k2_kv(const float* F, const float* ipb,
                                             const float* g1, const float* b1p,
                                             const float* WT, float* kmat, float* vmat){
  int r0 = blockIdx.x*8; int tid = threadIdx.x;
  __shared__ float xs[8][512];
  __shared__ float xl[8][512];
  __shared__ float red[8][64];
  __shared__ float mu8[8], rs8[8];
  for(int e=tid; e<4096; e+=512){ int r=e>>9, d=e&511; xs[r][d] = F[(size_t)(r0+r)*512 + d]; }
  __syncthreads();
  {
    int r = tid>>6, t = tid&63; float s=0.f, q=0.f;
    for(int i=0;i<8;++i){ float v = xs[r][t+64*i]; s+=v; q+=v*v; }
    red[r][t] = s; __syncthreads();
    if(tid<8){ float ss=0; for(int i=0;i<64;++i) ss+=red[tid][i]; mu8[tid]=ss*(1.f/512.f); }
    __syncthreads();
    red[r][t] = q; __syncthreads();
    if(tid<8){ float qq=0; for(int i=0;i<64;++i) qq+=red[tid][i];
      float m=mu8[tid]; rs8[tid]=1.f/sqrtf(fmaxf(qq*(1.f/512.f)-m*m,0.f)+1e-5f); }
    __syncthreads();
  }
  for(int e=tid; e<4096; e+=512){ int r=e>>9, d=e&511;
    xl[r][d] = (xs[r][d]-mu8[r])*rs8[r]*g1[d] + b1p[d]; }
  __syncthreads();
  int d=tid;
  float ak[8], av[8];
  float bk=ipb[512+d], bv=ipb[1024+d];
  #pragma unroll
  for(int r=0;r<8;++r){ ak[r]=bk; av[r]=bv; }
  for(int din=0; din<512; din+=4){
    float wk[4], wv[4];
    #pragma unroll
    for(int u=0;u<4;++u){ wk[u]=WT[(din+u)*1536+512+d]; wv[u]=WT[(din+u)*1536+1024+d]; }
    #pragma unroll
    for(int r=0;r<8;++r){
      float4 a4 = *(const float4*)&xl[r][din];
      float4 x4 = *(const float4*)&xs[r][din];
      ak[r] += a4.x*wk[0]+a4.y*wk[1]+a4.z*wk[2]+a4.w*wk[3];
      av[r] += x4.x*wv[0]+x4.y*wv[1]+x4.z*wv[2]+x4.w*wv[3];
    }
  }
  #pragma unroll
  for(int r=0;r<8;++r){
    size_t base = (size_t)(r0+r)*512;
    kmat[base+d]=ak[r]; vmat[base+d]=av[r];
  }
}

// ---------------- K3: scores + softmax (640 blocks: kc x b x h) ----------------
__global__ __launch_bounds__(256) void k3_attn(const float* qws, const float* kmat, float* attf){
  int bid = blockIdx.x;
  int kc = bid>>6, b = (bid>>3)&7, h = bid&7;
  int tid = threadIdx.x; int n = tid; int w = tid>>6, ln = tid&63;
  __shared__ float qb[8][64];
  __shared__ float rM[8][4], rS[8][4];
  float4 kr[16];
  if(n < 196){
    const float4* kp = (const float4*)(kmat + ((size_t)(b*196+n))*512 + h*64);
    #pragma unroll
    for(int j=0;j<16;++j) kr[j] = kp[j];
  }
  int kbase = kc*8;
  for(int e=tid; e<512; e+=256){ int kk=e>>6, j=e&63; int k=kbase+kk;
    qb[kk][j] = (k<77)? qws[k*512 + h*64 + j] : 0.f; }
  __syncthreads();
  float sc[8];
  #pragma unroll
  for(int kk=0;kk<8;++kk){
    float s = 0.f;
    if(n<196){
      const float4* q4 = (const float4*)qb[kk];
      #pragma unroll
      for(int j=0;j<16;++j){ float4 q = q4[j];
        s += q.x*kr[j].x + q.y*kr[j].y + q.z*kr[j].z + q.w*kr[j].w; }
      sc[kk] = s*0.125f;
    } else sc[kk] = -INFINITY;
  }
  #pragma unroll
  for(int kk=0;kk<8;++kk){ float m = wmaxf(sc[kk]); if(!ln) rM[kk][w]=m; }
  __syncthreads();
  float ex[8];
  #pragma unroll
  for(int kk=0;kk<8;++kk){
    float m = fmaxf(fmaxf(rM[kk][0],rM[kk][1]),fmaxf(rM[kk][2],rM[kk][3]));
    float e = expf(sc[kk]-m);
    ex[kk]=e;
    float s = wsumf(e); if(!ln) rS[kk][w]=s;
  }
  __syncthreads();
  #pragma unroll
  for(int kk=0;kk<8;++kk){
    int k = kbase+kk;
    if(k<77 && n<196){
      float tot = rS[kk][0]+rS[kk][1]+rS[kk][2]+rS[kk][3];
      attf[(((size_t)(b*8+h))*77 + k)*196 + n] = ex[kk]/tot;
    }
  }
}

// ---------------- K4: ctx = attn @ v (640 blocks: kc x b x h) ----------------
__global__ __launch_bounds__(256) void k4_ctx(const float* attf, const float* vmat, float* ctx){
  int bid = blockIdx.x;
  int kc = bid>>6, b = (bid>>3)&7, h = bid&7;
  int tid = threadIdx.x; int ng = tid>>6, j = tid&63;
  __shared__ float vT[196][64];
  __shared__ float aT[8][196];
  __shared__ float red[8][4][64];
  for(int e=tid; e<196*16; e+=256){ int n=e>>4, jc=e&15;
    const float4* vp = (const float4*)(vmat + ((size_t)(b*196+n))*512 + h*64);
    *(float4*)&vT[n][jc*4] = vp[jc];
  }
  int kbase=kc*8;
  for(int e=tid; e<8*196; e+=256){ int kk=e/196, n=e-kk*196; int k=kbase+kk;
    aT[kk][n] = (k<77)? attf[(((size_t)(b*8+h))*77+k)*196+n] : 0.f; }
  __syncthreads();
  float vr[49];
  #pragma unroll
  for(int t=0;t<49;++t) vr[t] = vT[ng*49+t][j];
  #pragma unroll
  for(int kk=0;kk<8;++kk){
    float p=0.f;
    #pragma unroll
    for(int t=0;t<49;++t) p += aT[kk][ng*49+t]*vr[t];
    red[kk][ng][j]=p;
  }
  __syncthreads();
  for(int e=tid; e<512; e+=256){ int kk=e>>6, j2=e&63; int k=kbase+kk;
    if(k<77){
      float s = red[kk][0][j2]+red[kk][1][j2]+red[kk][2][j2]+red[kk][3][j2];
      ctx[((size_t)(b*77+k))*512 + h*64 + j2] = s;
    } }
}

// ---------------- K5: attn_weights = mean over H ----------------
__global__ void k5_attw(const float* attf, float* attw, float* out2){
  int idx = blockIdx.x*256+threadIdx.x;
  if(idx >= 8*77*196) return;
  int b = idx / (77*196); int rem = idx - b*(77*196);
  float s=0.f;
  #pragma unroll
  for(int h=0;h<8;++h) s += attf[((size_t)(b*8+h))*77*196 + rem];
  s *= 0.125f;
  attw[idx]=s; out2[idx]=s;
}

// ---------------- K6: AO = LN2(ctx @ out_w^T + out_b)  (512 thr) ----------------
__global__ __launch_bounds__(512) void k6_ao(const float* ctx, const float* OWT,
                                             const float* ob, const float* g2, const float* b2p,
                                             float* AO){
  int R0 = blockIdx.x*8; int tid = threadIdx.x;
  __shared__ float xs[8][512];
  __shared__ float ao[8][512];
  __shared__ float red[8][64];
  __shared__ float mu8[8], rs8[8];
  for(int e=tid;e<4096;e+=512){ int r=e>>9,d=e&511; xs[r][d]=ctx[(size_t)(R0+r)*512+d]; }
  __syncthreads();
  int d=tid;
  float a[8]; float obv=ob[d];
  #pragma unroll
  for(int r=0;r<8;++r) a[r]=obv;
  for(int din=0;din<512;din+=4){
    float wv[4];
    #pragma unroll
    for(int u=0;u<4;++u) wv[u]=OWT[(din+u)*512+d];
    #pragma unroll
    for(int r=0;r<8;++r){
      float4 x4 = *(const float4*)&xs[r][din];
      a[r] += x4.x*wv[0]+x4.y*wv[1]+x4.z*wv[2]+x4.w*wv[3];
    }
  }
  #pragma unroll
  for(int r=0;r<8;++r) ao[r][d]=a[r];
  __syncthreads();
  {
    int r=tid>>6,t=tid&63; float s=0.f,q=0.f;
    for(int i=0;i<8;++i){ float v=ao[r][t+64*i]; s+=v; q+=v*v; }
    red[r][t]=s; __syncthreads();
    if(tid<8){ float ss=0; for(int i=0;i<64;++i) ss+=red[tid][i]; mu8[tid]=ss*(1.f/512.f); }
    __syncthreads(); red[r][t]=q; __syncthreads();
    if(tid<8){ float qq=0; for(int i=0;i<64;++i) qq+=red[tid][i];
      float m=mu8[tid]; rs8[tid]=1.f/sqrtf(fmaxf(qq*(1.f/512.f)-m*m,0.f)+1e-5f); }
    __syncthreads();
  }
  for(int e=tid;e<4096;e+=512){ int r=e>>9,dd=e&511;
    AO[(size_t)(R0+r)*512+dd] = (ao[r][dd]-mu8[r])*rs8[r]*g2[dd] + b2p[dd]; }
}

// ---------------- K6b: Sv = (1/77) attw^T @ AO per (b, 8-n tile); wsum ---------
__global__ __launch_bounds__(512) void k6b_sv(const float* AO, const float* attw,
                                              float* Svws, float* wsumws){
  int bid = blockIdx.x;
  int b = bid/25, nt = bid - b*25;
  int n0 = nt*8;
  int tid = threadIdx.x;
  __shared__ float wsK[80][8];
  for(int e=tid; e<640; e+=512){ int k=e>>3, r=e&7; int n=n0+r;
    wsK[k][r] = (k<77 && n<196)? attw[((size_t)(b*77+k))*196 + n] : 0.f; }
  __syncthreads();
  if(tid<8){ int n=n0+tid;
    if(n<196){ float s=0.f;
      for(int k=0;k<77;++k) s+=wsK[k][tid];
      wsumws[b*196+n]=s; } }
  int d = tid;
  float acc[8];
  #pragma unroll
  for(int r=0;r<8;++r) acc[r]=0.f;
  const float* aob = AO + (size_t)b*77*512 + d;
  for(int k=0;k<77;++k){
    float a = aob[(size_t)k*512];
    #pragma unroll
    for(int r=0;r<8;++r) acc[r] += wsK[k][r]*a;
  }
  #pragma unroll
  for(int r=0;r<8;++r){ int n=n0+r; if(n<196)
    Svws[((size_t)(b*196+n))*512 + d] = acc[r]*(1.f/77.f); }
}

// ---------------- K7: per-(b,n,third) fused MLP; A LDS-resident, barrier-free t-loop
// 3-way row split: third 0 = rows 0..31 (MT=2), third 1 = rows 32..63 (MT=2),
// third 2 = rows 64..79 (MT=1). A-LDS = 64KB (MT=2), struct 77.6KB -> exactly
// 2 blocks/CU -> 16 waves/CU -> backend VGPR cap 128 (R9/R11-proven mechanism).
// Stage once (coalesced, (lane+t)&63 rotation = bank-uniform), then
// {ds_read A, global B 2-set register dbuf, MFMA} with ZERO barriers.
struct __align__(16) K7Smem {
  _Float16 Ah[2*16*512];    // [mt][t][pos 0..63][8], pos=(lane+t)&63
  _Float16 Al[2*16*512];
  float b1s[512], gs[512], bs[512];
  float wvS[80];
  float redS[8][32], redQ[8][32];
  float muA[32], rsA[32];
  float gfin[512];
  float qred[320];
};   // 77.6 KB -> 2 blocks/CU

#define K7_MFMA3(ACC, AFH, AFL, BH, BL) \
  ACC = __builtin_amdgcn_mfma_f32_16x16x32_f16(AFL, BH, ACC, 0,0,0); \
  ACC = __builtin_amdgcn_mfma_f32_16x16x32_f16(AFH, BL, ACC, 0,0,0); \
  ACC = __builtin_amdgcn_mfma_f32_16x16x32_f16(AFH, BH, ACC, 0,0,0);

struct Bset { f16x8 h0,h1,h2,h3,l0,l1,l2,l3; };

DI void loadB(Bset& s, const _Float16* bph, const _Float16* bpl, int t){
  const _Float16* ph = bph + t*16384;
  const _Float16* pl = bpl + t*16384;
  s.h0 = *(const f16x8*)(ph);       s.h1 = *(const f16x8*)(ph+512);
  s.h2 = *(const f16x8*)(ph+1024);  s.h3 = *(const f16x8*)(ph+1536);
  s.l0 = *(const f16x8*)(pl);       s.l1 = *(const f16x8*)(pl+512);
  s.l2 = *(const f16x8*)(pl+1024);  s.l3 = *(const f16x8*)(pl+1536);
}

template<int MT>
DI void stepMFMA(f32x4 acc[][4], const _Float16* Ah, const _Float16* Al,
                 const Bset& B, int t, int ln){
  #pragma unroll
  for(int mt=0; mt<MT; ++mt){
    int off = (mt*16 + t)*512 + ((ln + t)&63)*8;
    f16x8 fh = *(const f16x8*)&Ah[off];
    f16x8 fl = *(const f16x8*)&Al[off];
    K7_MFMA3(acc[mt][0], fh, fl, B.h0, B.l0)
    K7_MFMA3(acc[mt][1], fh, fl, B.h1, B.l1)
    K7_MFMA3(acc[mt][2], fh, fl, B.h2, B.l2)
    K7_MFMA3(acc[mt][3], fh, fl, B.h3, B.l3)
  }
}

template<int MT, int K0>
DI void k7_body(int bn, const float* F, const float* AO, const float* attw,
                const _Float16* w1hi, const _Float16* w1lo,
                const float* b1p, const float* lng, const float* lnb,
                const float* w2, const float* b2p,
                const float* Svws, const float* wsumws,
                float* Qpws, K7Smem& sm){
  int b = bn/196, n = bn - b*196;
  int tid = threadIdx.x; int w = tid>>6, ln = tid&63;
  int col = ln&15, quad = ln>>4;
  const float* AObase = AO + (size_t)b*77*512;
  sm.b1s[tid] = b1p[tid]; sm.gs[tid] = lng[tid]; sm.bs[tid] = lnb[tid];
  if(tid<80) sm.wvS[tid] = (tid<77)? attw[((size_t)(b*77+tid))*196+n] : 0.f;
  __syncthreads();

  // ---- stage clean (hi/lo) for MT*16 rows into LDS; this thread owns fixed d0
  {
    int d0 = (tid&63)*8;            // fixed k-slice for this thread
    int r0 = tid>>6;                // base row 0..7 (+8 per step)
    int t  = d0>>5;
    int k8 = (d0&31)>>3;
    float4 f0 = *(const float4*)&F[(size_t)bn*512 + d0];
    float4 f1 = *(const float4*)&F[(size_t)bn*512 + d0+4];
    float4 sv0 = *(const float4*)&Svws[(size_t)bn*512 + d0];
    float4 sv1 = *(const float4*)&Svws[(size_t)bn*512 + d0+4];
    float fk[8] = {f0.x*1024.f,f0.y*1024.f,f0.z*1024.f,f0.w*1024.f,
                   f1.x*1024.f,f1.y*1024.f,f1.z*1024.f,f1.w*1024.f};
    float sv[8] = {sv0.x,sv0.y,sv0.z,sv0.w,sv1.x,sv1.y,sv1.z,sv1.w};
    #pragma unroll
    for(int it=0; it<MT*2; ++it){
      int row = r0 + it*8;          // local row 0..MT*16-1
      int grow = K0 + row;
      bool ok = grow < 77;
      int rl = ok ? grow : 0;
      float wm = ok ? sm.wvS[grow] : 0.f;
      const float* ap = AObase + (size_t)rl*512 + d0;
      float4 a0 = *(const float4*)ap;
      float4 a1 = *(const float4*)(ap+4);
      float av[8] = {a0.x,a0.y,a0.z,a0.w,a1.x,a1.y,a1.z,a1.w};
      f16x8 hfrag, lfrag;
      #pragma unroll
      for(int i=0;i<8;++i){
        float c = ok ? fk[i]*(wm*av[i] - sv[i]) : 0.f;
        _Float16 h = (_Float16)c;
        hfrag[i] = h;
        lfrag[i] = (_Float16)(c - (float)h);
      }
      int lane = (row&15) | (k8<<4);
      int pos = (lane + t)&63;
      int idx = (((row>>4)*16 + t)*512) + pos*8;
      *(f16x8*)&sm.Ah[idx] = hfrag;
      *(f16x8*)&sm.Al[idx] = lfrag;
    }
  }
  __syncthreads();
  // ---- barrier-free t-loop: A from LDS, B double-buffered from global ----
  f32x4 acc[MT][4];
  #pragma unroll
  for(int mt=0;mt<MT;++mt)
    #pragma unroll
    for(int jj=0;jj<4;++jj) acc[mt][jj] = (f32x4){0.f,0.f,0.f,0.f};

  const _Float16* bph = w1hi + ((w*4)*64 + ln)*8;  // +512 per jj, +16384 per t
  const _Float16* bpl = w1lo + ((w*4)*64 + ln)*8;

  Bset s0, s1;
  loadB(s0, bph, bpl, 0);
  #pragma unroll 1
  for(int tt=0; tt<16; tt+=2){
    loadB(s1, bph, bpl, tt+1);                 // prefetch odd step
    stepMFMA<MT>(acc, sm.Ah, sm.Al, s0, tt, ln);
    if(tt+2<16) loadB(s0, bph, bpl, tt+2);     // prefetch next even step
    stepMFMA<MT>(acc, sm.Ah, sm.Al, s1, tt+1, ln);
  }

  const float UNS = 1.f/65536.f;
  #pragma unroll
  for(int mt=0;mt<MT;++mt){
    float s[4]={0.f,0.f,0.f,0.f}, q[4]={0.f,0.f,0.f,0.f};
    #pragma unroll
    for(int jj=0;jj<4;++jj){
      int j = w*64 + jj*16 + col; float bj = sm.b1s[j];
      #pragma unroll
      for(int r=0;r<4;++r){
        float h = acc[mt][jj][r]*UNS + bj;
        s[r]+=h; q[r]+=h*h;
      }
    }
    #pragma unroll
    for(int r=0;r<4;++r){
      #pragma unroll
      for(int o=1;o<16;o<<=1){ s[r]+=__shfl_xor(s[r],o,64); q[r]+=__shfl_xor(q[r],o,64); }
    }
    if(col==0){
      #pragma unroll
      for(int r=0;r<4;++r){ int row = mt*16+quad*4+r; sm.redS[w][row]=s[r]; sm.redQ[w][row]=q[r]; }
    }
  }
  __syncthreads();
  if(tid<MT*16){
    float s=0.f,q=0.f;
    #pragma unroll
    for(int ww=0;ww<8;++ww){ s+=sm.redS[ww][tid]; q+=sm.redQ[ww][tid]; }
    float mu = s*(1.f/512.f);
    float var = q*(1.f/512.f)-mu*mu;
    sm.muA[tid]=mu; sm.rsA[tid]=1.f/sqrtf(fmaxf(var,0.f)+1e-5f);
  }
  __syncthreads();
  float gp[4]={0.f,0.f,0.f,0.f};
  #pragma unroll
  for(int mt=0;mt<MT;++mt){
    #pragma unroll
    for(int r=0;r<4;++r){
      int lr = mt*16+quad*4+r;
      float mu=sm.muA[lr], rs=sm.rsA[lr], wk=sm.wvS[K0+lr];
      #pragma unroll
      for(int jj=0;jj<4;++jj){
        int j = w*64 + jj*16 + col;
        float h = acc[mt][jj][r]*UNS + sm.b1s[j];
        float x = (h-mu)*rs;
        float y = x*sm.gs[j]+sm.bs[j];
        float gl = 0.5f*y*(1.f+erff(y*0.70710678118654752f));
        gp[jj] += wk*gl;
      }
    }
  }
  #pragma unroll
  for(int jj=0;jj<4;++jj){ gp[jj]+=__shfl_xor(gp[jj],16,64); gp[jj]+=__shfl_xor(gp[jj],32,64); }
  if(ln<16){
    #pragma unroll
    for(int jj=0;jj<4;++jj) sm.gfin[w*64 + jj*16 + ln] = gp[jj];
  }
  __syncthreads();
  if(tid<320){ int m=tid>>4, seg=tid&15; float p=0.f;
    for(int u=0;u<32;++u){ int j=seg*32+u; p += sm.gfin[j]*w2[m*512+j]; }
    sm.qred[m*16+seg]=p; }
  __syncthreads();
  if(tid<20){ float s=0.f;
    for(int seg=0;seg<16;++seg) s+=sm.qred[tid*16+seg];
    if(K0==0) s += b2p[tid]*wsumws[bn];          // bias term once, in third 0
    Qpws[(size_t)bn*60 + (K0==0?0:(K0==32?20:40)) + tid]=s; }
}

__global__
__attribute__((amdgpu_flat_work_group_size(512,512)))
void k7_mlp(const float* F, const float* AO, const float* attw,
            const _Float16* w1hi, const _Float16* w1lo,
            const float* b1p, const float* lng, const float* lnb,
            const float* w2, const float* b2p,
            const float* Svws, const float* wsumws,
            float* Qpws){
  __shared__ K7Smem sm;
  int bid = blockIdx.x;
  int bn = bid/3;
  int third = bid - bn*3;
  if(third==0)      k7_body<2,0 >(bn,F,AO,attw,w1hi,w1lo,b1p,lng,lnb,w2,b2p,Svws,wsumws,Qpws,sm);
  else if(third==1) k7_body<2,32>(bn,F,AO,attw,w1hi,w1lo,b1p,lng,lnb,w2,b2p,Svws,wsumws,Qpws,sm);
  else              k7_body<1,64>(bn,F,AO,attw,w1hi,w1lo,b1p,lng,lnb,w2,b2p,Svws,wsumws,Qpws,sm);
}

// ---------------- K8: per-(b,n) top-51 mask + normalize -> out1 ----------------
__global__ __launch_bounds__(256) void k8_topk(const float* F, const float* T,
                                               const float* Qpws, float* out1){
  int bn = blockIdx.x; int tid = threadIdx.x;
  int w = tid>>6, ln = tid&63;
  __shared__ float Fv[512];
  __shared__ float QpS[20];
  __shared__ float ninv[20];
  __shared__ unsigned char selb[20][64];
  for(int e=tid;e<512;e+=256) Fv[e]=F[(size_t)bn*512+e];
  if(tid<20) QpS[tid]=Qpws[(size_t)bn*60+tid] + Qpws[(size_t)bn*60+20+tid] + Qpws[(size_t)bn*60+40+tid];
  __syncthreads();
  for(int rr=0; rr<5; ++rr){
    int m = rr*4 + w;
    float qv[8]; uint key[8];
    const float4* tp = (const float4*)(T + (size_t)m*512 + ln*8);
    float4 t0 = tp[0], t1 = tp[1];
    float tf[8] = {t0.x,t0.y,t0.z,t0.w,t1.x,t1.y,t1.z,t1.w};
    float qp = QpS[m];
    #pragma unroll
    for(int i=0;i<8;++i){ float p = Fv[ln*8+i]*tf[i]; qv[i]=p*qp;
      key[i]=__float_as_uint(qv[i])&0x7fffffffu; }
    uint th=0u;
    for(int bit=30; bit>=0; --bit){
      uint cand = th | (1u<<bit);
      int c=0;
      #pragma unroll
      for(int i=0;i<8;++i) c += (key[i]>=cand);
      c = wsumi(c);
      if(c>=51) th=cand;
    }
    int cg=0;
    #pragma unroll
    for(int i=0;i<8;++i) cg += (key[i]>th);
    cg = wsumi(cg);
    int rneed = 51-cg;
    int eqc=0;
    #pragma unroll
    for(int i=0;i<8;++i) eqc += (key[i]==th);
    int pre=eqc;
    for(int o=1;o<64;o<<=1){ int v=__shfl_up(pre,o,64); if(ln>=o) pre+=v; }
    pre -= eqc;
    unsigned char mbits=0; float ss=0.f; int rk=pre;
    #pragma unroll
    for(int i=0;i<8;++i){
      bool s;
      if(key[i]>th) s=true;
      else if(key[i]==th){ s = (rk<rneed); rk++; }
      else s=false;
      if(s){ mbits |= (unsigned char)(1u<<i); ss += qv[i]*qv[i]; }
    }
    ss = wsumf(ss);
    if(ln==0) ninv[m] = 1.f/fmaxf(sqrtf(ss),1e-6f);
    selb[m][ln]=mbits;
  }
  __syncthreads();
  size_t base=(size_t)bn*10240;
  for(int e=tid;e<10240;e+=256){
    int d=e/20, mm=e-d*20;
    float val=0.f;
    if((selb[mm][d>>3]>>(d&7))&1){
      val = Fv[d]*T[(size_t)mm*512+d]*QpS[mm]*ninv[mm];
    }
    out1[base+e]=val;
  }
}

extern "C" void kernel_launch(void* const* d_in, const int* in_sizes, int n_in,
                              void* d_out, int out_size, void* d_ws, size_t ws_size,
                              hipStream_t stream){
  const float* F    = (const float*)d_in[0];
  const float* text = (const float*)d_in[1];
  const float* ipw  = (const float*)d_in[2];
  const float* ipb  = (const float*)d_in[3];
  const float* outw = (const float*)d_in[4];
  const float* outb = (const float*)d_in[5];
  const float* g1   = (const float*)d_in[6];
  const float* b1   = (const float*)d_in[7];
  const float* g2   = (const float*)d_in[8];
  const float* b2   = (const float*)d_in[9];
  const float* mw1  = (const float*)d_in[10];
  const float* mb1  = (const float*)d_in[11];
  const float* mlg  = (const float*)d_in[12];
  const float* mlb  = (const float*)d_in[13];
  const float* mw2  = (const float*)d_in[14];
  const float* mb2  = (const float*)d_in[15];
  const float* tmpl = (const float*)d_in[16];
  float* ws = (float*)d_ws;
  float* WT   = ws;
  float* OWT  = ws +  786432;
  float* qws  = ws + 1048576;
  float* kmat = ws + 1088000;
  float* vmat = ws + 1890816;
  float* attf = ws + 2693632;
  float* attw = ws + 3659520;
  float* ctx  = ws + 3780256;
  float* AO   = ws + 4095648;
  _Float16* w1hi = (_Float16*)(ws + 4473760);
  _Float16* w1lo = (_Float16*)(ws + 4604832);
  // dead-region reuse:
  float* wsum = ws + 1048576;   // old qws region (dead after k3)
  float* Sv   = ws + 1088000;   // old kmat region (dead after k3, exact fit)
  float* Qp   = ws +  786432;   // old OWT region (dead after k6; need 94080 fl <= 262144)
  float* out1 = (float*)d_out;
  float* out2 = out1 + 16056320;

  hipLaunchKernelGGL(k0_transpose, dim3(2048), dim3(256), 0, stream, ipw, outw, mw1, WT, OWT, w1hi, w1lo);
  hipLaunchKernelGGL(k1_q,   dim3(154), dim3(256), 0, stream, text, ipb, g1, b1, WT, qws);
  hipLaunchKernelGGL(k2_kv,  dim3(196), dim3(512), 0, stream, F, ipb, g1, b1, WT, kmat, vmat);
  hipLaunchKernelGGL(k3_attn,dim3(640), dim3(256), 0, stream, qws, kmat, attf);
  hipLaunchKernelGGL(k4_ctx, dim3(640), dim3(256), 0, stream, attf, vmat, ctx);
  hipLaunchKernelGGL(k5_attw,dim3(472), dim3(256), 0, stream, attf, attw, out2);
  hipLaunchKernelGGL(k6_ao,  dim3(77),  dim3(512), 0, stream, ctx, OWT, outb, g2, b2, AO);
  hipLaunchKernelGGL(k6b_sv, dim3(200), dim3(512), 0, stream, AO, attw, Sv, wsum);
  hipLaunchKernelGGL(k7_mlp, dim3(4704),dim3(512), 0, stream, F, AO, attw, w1hi, w1lo, mb1, mlg, mlb, mw2, mb2, Sv, wsum, Qp);
  hipLaunchKernelGGL(k8_topk,dim3(1568),dim3(256), 0, stream, F, tmpl, Qp, out1);
}

// Round 7
// 669.050 us; speedup vs baseline: 1.3904x; 1.0285x over previous
//
#include <hip/hip_runtime.h>
#include <hip/hip_bf16.h>
#include <math.h>

// B=8 N=196 D=512 M=20 K=77 H=8 hd=64, keep=51.  All inputs/outputs fp32.
// out1 = Qs/nrm (B,N,D,M) 16,056,320 fl; out2 = attn_weights (B,K,N) 120,736 fl
// Workspace layout: see kernel_launch. Dead-region reuse:
//   wsum -> qws (@1048576, dead after k3), Sv -> kmat (@1088000, dead after k3),
//   Qp -> OWT (@786432, dead after k6).
//
// R13 (from R12 counters: k7 267us MfmaUtil 35 Occ 42 VGPR 64 no-spill;
// bank-conflicts 11.35M traced to qred's wave-uniform-u reads; B-prefetch
// only 1-deep vs ~250cy L2 latency; k2 = 196 blocks on 256 CUs):
//  1. k7 t-loop: 4 B-sets, depth-2 prefetch (cap 128 allows ~115 live).
//  2. k7 qred: u'=(u+seg)&31 rotation -> per-lane distinct banks.
//  3. k2: 4 rows/block -> 392 blocks (all CUs busy, half the serial chain).
//  4. k8: ballot+popcount for threshold counting (replaces shfl-reduce).

typedef unsigned int uint;
typedef _Float16 f16x8 __attribute__((ext_vector_type(8)));
typedef float f32x4 __attribute__((ext_vector_type(4)));

#define DI __device__ __forceinline__

DI float wsumf(float v){ for(int o=32;o>0;o>>=1) v += __shfl_xor(v,o,64); return v; }
DI int   wsumi(int v){ for(int o=32;o>0;o>>=1) v += __shfl_xor(v,o,64); return v; }
DI float wmaxf(float v){ for(int o=32;o>0;o>>=1) v = fmaxf(v,__shfl_xor(v,o,64)); return v; }

// ---------------- K0: tiled transposes + W1 split/swizzle ----------------
__global__ __launch_bounds__(256) void k0_transpose(const float* ipw, const float* ow, const float* mw1,
                             float* WT, float* OWT, _Float16* w1hi, _Float16* w1lo){
  int bid = blockIdx.x;
  if(bid < 768){
    __shared__ float t[32][33];
    int tdin = bid & 15, tdout = bid >> 4;
    int tx = threadIdx.x & 31, ty = threadIdx.x >> 5;
    int dout0 = tdout*32, din0 = tdin*32;
    for(int r=ty; r<32; r+=8) t[r][tx] = ipw[(size_t)(dout0+r)*512 + din0+tx];
    __syncthreads();
    for(int r=ty; r<32; r+=8) WT[(size_t)(din0+r)*1536 + dout0+tx] = t[tx][r];
  } else if(bid < 1024){
    __shared__ float t[32][33];
    int b2 = bid - 768;
    int tdin = b2 & 15, tdout = b2 >> 4;
    int tx = threadIdx.x & 31, ty = threadIdx.x >> 5;
    int dout0 = tdout*32, din0 = tdin*32;
    for(int r=ty; r<32; r+=8) t[r][tx] = ow[(size_t)(dout0+r)*512 + din0+tx];
    __syncthreads();
    for(int r=ty; r<32; r+=8) OWT[(size_t)(din0+r)*512 + dout0+tx] = t[tx][r];
  } else {
    int i3 = (bid-1024)*256 + threadIdx.x;
    int t = i3&7, ln = (i3>>3)&63, J = (i3>>9)&31, T = i3>>14;
    int j = J*16 + (ln&15);
    int d = T*32 + ((ln>>4)<<3) + t;
    float w = mw1[j*512 + d] * 64.0f;
    _Float16 hi = (_Float16)w;
    _Float16 lo = (_Float16)(w - (float)hi);
    w1hi[i3] = hi; w1lo[i3] = lo;
  }
}

// ---------------- K1: q = LN(text) @ Wq^T + bq  (154 blocks: k x half) ----------------
__global__ __launch_bounds__(256) void k1_q(const float* text, const float* ipb,
                                            const float* g1, const float* b1p,
                                            const float* WT, float* qws){
  int k = blockIdx.x >> 1, half = blockIdx.x & 1;
  int tid = threadIdx.x;
  __shared__ float xln[512];
  __shared__ float rA[4], rB[4];
  float x0 = text[k*512+tid], x1 = text[k*512+256+tid];
  float s1 = wsumf(x0+x1), s2 = wsumf(x0*x0+x1*x1);
  int w = tid>>6, ln = tid&63;
  if(!ln){ rA[w]=s1; rB[w]=s2; }
  __syncthreads();
  float mu = (rA[0]+rA[1]+rA[2]+rA[3])*(1.f/512.f);
  float var = (rB[0]+rB[1]+rB[2]+rB[3])*(1.f/512.f) - mu*mu;
  float rs = 1.f/sqrtf(fmaxf(var,0.f) + 1e-5f);
  xln[tid]     = (x0-mu)*rs*g1[tid]     + b1p[tid];
  xln[tid+256] = (x1-mu)*rs*g1[tid+256] + b1p[tid+256];
  __syncthreads();
  int d = half*256 + tid;
  float a0=0.f,a1=0.f,a2=0.f,a3=0.f;   // 4 independent chains for ILP
  for(int din=0; din<512; din+=4){
    a0 += xln[din  ] * WT[(din  )*1536 + d];
    a1 += xln[din+1] * WT[(din+1)*1536 + d];
    a2 += xln[din+2] * WT[(din+2)*1536 + d];
    a3 += xln[din+3] * WT[(din+3)*1536 + d];
  }
  qws[k*512+d] = ipb[d] + ((a0+a1)+(a2+a3));
}

// ---------------- K2: k = LN(F)@Wk^T+bk, v = F@Wv^T+bv  (4 rows/block, 392 blocks) ----
__global__ __launch_bounds__(512) void k2_kv(const float* F, const float* ipb,
                                             const float* g1, const float* b1p,
                                             const float* WT, float* kmat, float* vmat){
  int r0 = blockIdx.x*4; int tid = threadIdx.x;
  __shared__ float xs[4][512];
  __shared__ float xl[4][512];
  __shared__ float red[4][64];
  __shared__ float mu4[4], rs4[4];
  for(int e=tid; e<2048; e+=512){ int r=e>>9, d=e&511; xs[r][d] = F[(size_t)(r0+r)*512 + d]; }
  __syncthreads();
  {
    float s=0.f, q=0.f; int r=0, t=0;
    if(tid<256){
      r = tid>>6; t = tid&63;
      for(int i=0;i<8;++i){ float v = xs[r][t+64*i]; s+=v; q+=v*v; }
      red[r][t] = s;
    }
    __syncthreads();
    if(tid<4){ float ss=0; for(int i=0;i<64;++i) ss+=red[tid][i]; mu4[tid]=ss*(1.f/512.f); }
    __syncthreads();
    if(tid<256) red[r][t] = q;
    __syncthreads();
    if(tid<4){ float qq=0; for(int i=0;i<64;++i) qq+=red[tid][i];
      float m=mu4[tid]; rs4[tid]=1.f/sqrtf(fmaxf(qq*(1.f/512.f)-m*m,0.f)+1e-5f); }
    __syncthreads();
  }
  for(int e=tid; e<2048; e+=512){ int r=e>>9, d=e&511;
    xl[r][d] = (xs[r][d]-mu4[r])*rs4[r]*g1[d] + b1p[d]; }
  __syncthreads();
  int d=tid;
  float ak[4], av[4];
  float bk=ipb[512+d], bv=ipb[1024+d];
  #pragma unroll
  for(int r=0;r<4;++r){ ak[r]=bk; av[r]=bv; }
  for(int din=0; din<512; din+=4){
    float wk[4], wv[4];
    #pragma unroll
    for(int u=0;u<4;++u){ wk[u]=WT[(din+u)*1536+512+d]; wv[u]=WT[(din+u)*1536+1024+d]; }
    #pragma unroll
    for(int r=0;r<4;++r){
      float4 a4 = *(const float4*)&xl[r][din];
      float4 x4 = *(const float4*)&xs[r][din];
      ak[r] += a4.x*wk[0]+a4.y*wk[1]+a4.z*wk[2]+a4.w*wk[3];
      av[r] += x4.x*wv[0]+x4.y*wv[1]+x4.z*wv[2]+x4.w*wv[3];
    }
  }
  #pragma unroll
  for(int r=0;r<4;++r){
    size_t base = (size_t)(r0+r)*512;
    kmat[base+d]=ak[r]; vmat[base+d]=av[r];
  }
}

// ---------------- K3: scores + softmax (640 blocks: kc x b x h) ----------------
__global__ __launch_bounds__(256) void k3_attn(const float* qws, const float* kmat, float* attf){
  int bid = blockIdx.x;
  int kc = bid>>6, b = (bid>>3)&7, h = bid&7;
  int tid = threadIdx.x; int n = tid; int w = tid>>6, ln = tid&63;
  __shared__ float qb[8][64];
  __shared__ float rM[8][4], rS[8][4];
  float4 kr[16];
  if(n < 196){
    const float4* kp = (const float4*)(kmat + ((size_t)(b*196+n))*512 + h*64);
    #pragma unroll
    for(int j=0;j<16;++j) kr[j] = kp[j];
  }
  int kbase = kc*8;
  for(int e=tid; e<512; e+=256){ int kk=e>>6, j=e&63; int k=kbase+kk;
    qb[kk][j] = (k<77)? qws[k*512 + h*64 + j] : 0.f; }
  __syncthreads();
  float sc[8];
  #pragma unroll
  for(int kk=0;kk<8;++kk){
    float s = 0.f;
    if(n<196){
      const float4* q4 = (const float4*)qb[kk];
      #pragma unroll
      for(int j=0;j<16;++j){ float4 q = q4[j];
        s += q.x*kr[j].x + q.y*kr[j].y + q.z*kr[j].z + q.w*kr[j].w; }
      sc[kk] = s*0.125f;
    } else sc[kk] = -INFINITY;
  }
  #pragma unroll
  for(int kk=0;kk<8;++kk){ float m = wmaxf(sc[kk]); if(!ln) rM[kk][w]=m; }
  __syncthreads();
  float ex[8];
  #pragma unroll
  for(int kk=0;kk<8;++kk){
    float m = fmaxf(fmaxf(rM[kk][0],rM[kk][1]),fmaxf(rM[kk][2],rM[kk][3]));
    float e = expf(sc[kk]-m);
    ex[kk]=e;
    float s = wsumf(e); if(!ln) rS[kk][w]=s;
  }
  __syncthreads();
  #pragma unroll
  for(int kk=0;kk<8;++kk){
    int k = kbase+kk;
    if(k<77 && n<196){
      float tot = rS[kk][0]+rS[kk][1]+rS[kk][2]+rS[kk][3];
      attf[(((size_t)(b*8+h))*77 + k)*196 + n] = ex[kk]/tot;
    }
  }
}

// ---------------- K4: ctx = attn @ v (640 blocks: kc x b x h) ----------------
__global__ __launch_bounds__(256) void k4_ctx(const float* attf, const float* vmat, float* ctx){
  int bid = blockIdx.x;
  int kc = bid>>6, b = (bid>>3)&7, h = bid&7;
  int tid = threadIdx.x; int ng = tid>>6, j = tid&63;
  __shared__ float vT[196][64];
  __shared__ float aT[8][196];
  __shared__ float red[8][4][64];
  for(int e=tid; e<196*16; e+=256){ int n=e>>4, jc=e&15;
    const float4* vp = (const float4*)(vmat + ((size_t)(b*196+n))*512 + h*64);
    *(float4*)&vT[n][jc*4] = vp[jc];
  }
  int kbase=kc*8;
  for(int e=tid; e<8*196; e+=256){ int kk=e/196, n=e-kk*196; int k=kbase+kk;
    aT[kk][n] = (k<77)? attf[(((size_t)(b*8+h))*77+k)*196+n] : 0.f; }
  __syncthreads();
  float vr[49];
  #pragma unroll
  for(int t=0;t<49;++t) vr[t] = vT[ng*49+t][j];
  #pragma unroll
  for(int kk=0;kk<8;++kk){
    float p=0.f;
    #pragma unroll
    for(int t=0;t<49;++t) p += aT[kk][ng*49+t]*vr[t];
    red[kk][ng][j]=p;
  }
  __syncthreads();
  for(int e=tid; e<512; e+=256){ int kk=e>>6, j2=e&63; int k=kbase+kk;
    if(k<77){
      float s = red[kk][0][j2]+red[kk][1][j2]+red[kk][2][j2]+red[kk][3][j2];
      ctx[((size_t)(b*77+k))*512 + h*64 + j2] = s;
    } }
}

// ---------------- K5: attn_weights = mean over H ----------------
__global__ void k5_attw(const float* attf, float* attw, float* out2){
  int idx = blockIdx.x*256+threadIdx.x;
  if(idx >= 8*77*196) return;
  int b = idx / (77*196); int rem = idx - b*(77*196);
  float s=0.f;
  #pragma unroll
  for(int h=0;h<8;++h) s += attf[((size_t)(b*8+h))*77*196 + rem];
  s *= 0.125f;
  attw[idx]=s; out2[idx]=s;
}

// ---------------- K6: AO = LN2(ctx @ out_w^T + out_b)  (512 thr) ----------------
__global__ __launch_bounds__(512) void k6_ao(const float* ctx, const float* OWT,
                                             const float* ob, const float* g2, const float* b2p,
                                             float* AO){
  int R0 = blockIdx.x*8; int tid = threadIdx.x;
  __shared__ float xs[8][512];
  __shared__ float ao[8][512];
  __shared__ float red[8][64];
  __shared__ float mu8[8], rs8[8];
  for(int e=tid;e<4096;e+=512){ int r=e>>9,d=e&511; xs[r][d]=ctx[(size_t)(R0+r)*512+d]; }
  __syncthreads();
  int d=tid;
  float a[8]; float obv=ob[d];
  #pragma unroll
  for(int r=0;r<8;++r) a[r]=obv;
  for(int din=0;din<512;din+=4){
    float wv[4];
    #pragma unroll
    for(int u=0;u<4;++u) wv[u]=OWT[(din+u)*512+d];
    #pragma unroll
    for(int r=0;r<8;++r){
      float4 x4 = *(const float4*)&xs[r][din];
      a[r] += x4.x*wv[0]+x4.y*wv[1]+x4.z*wv[2]+x4.w*wv[3];
    }
  }
  #pragma unroll
  for(int r=0;r<8;++r) ao[r][d]=a[r];
  __syncthreads();
  {
    int r=tid>>6,t=tid&63; float s=0.f,q=0.f;
    for(int i=0;i<8;++i){ float v=ao[r][t+64*i]; s+=v; q+=v*v; }
    red[r][t]=s; __syncthreads();
    if(tid<8){ float ss=0; for(int i=0;i<64;++i) ss+=red[tid][i]; mu8[tid]=ss*(1.f/512.f); }
    __syncthreads(); red[r][t]=q; __syncthreads();
    if(tid<8){ float qq=0; for(int i=0;i<64;++i) qq+=red[tid][i];
      float m=mu8[tid]; rs8[tid]=1.f/sqrtf(fmaxf(qq*(1.f/512.f)-m*m,0.f)+1e-5f); }
    __syncthreads();
  }
  for(int e=tid;e<4096;e+=512){ int r=e>>9,dd=e&511;
    AO[(size_t)(R0+r)*512+dd] = (ao[r][dd]-mu8[r])*rs8[r]*g2[dd] + b2p[dd]; }
}

// ---------------- K6b: Sv = (1/77) attw^T @ AO per (b, 8-n tile); wsum ---------
__global__ __launch_bounds__(512) void k6b_sv(const float* AO, const float* attw,
                                              float* Svws, float* wsumws){
  int bid = blockIdx.x;
  int b = bid/25, nt = bid - b*25;
  int n0 = nt*8;
  int tid = threadIdx.x;
  __shared__ float wsK[80][8];
  for(int e=tid; e<640; e+=512){ int k=e>>3, r=e&7; int n=n0+r;
    wsK[k][r] = (k<77 && n<196)? attw[((size_t)(b*77+k))*196 + n] : 0.f; }
  __syncthreads();
  if(tid<8){ int n=n0+tid;
    if(n<196){ float s=0.f;
      for(int k=0;k<77;++k) s+=wsK[k][tid];
      wsumws[b*196+n]=s; } }
  int d = tid;
  float acc[8];
  #pragma unroll
  for(int r=0;r<8;++r) acc[r]=0.f;
  const float* aob = AO + (size_t)b*77*512 + d;
  for(int k=0;k<77;++k){
    float a = aob[(size_t)k*512];
    #pragma unroll
    for(int r=0;r<8;++r) acc[r] += wsK[k][r]*a;
  }
  #pragma unroll
  for(int r=0;r<8;++r){ int n=n0+r; if(n<196)
    Svws[((size_t)(b*196+n))*512 + d] = acc[r]*(1.f/77.f); }
}

// ---------------- K7: per-(b,n,third) fused MLP; A LDS-resident, barrier-free t-loop
// 3-way row split: thirds (MT=2,2,1). A-LDS 64KB (MT=2), struct 77.6KB ->
// 2 blocks/CU -> VGPR cap 128. t-loop: depth-2 B prefetch (4 named Bsets,
// ~115 VGPR live), ds_read A, MFMA, zero barriers.
struct __align__(16) K7Smem {
  _Float16 Ah[2*16*512];    // [mt][t][pos 0..63][8], pos=(lane+t)&63
  _Float16 Al[2*16*512];
  float b1s[512], gs[512], bs[512];
  float wvS[80];
  float redS[8][32], redQ[8][32];
  float muA[32], rsA[32];
  float gfin[512];
  float qred[320];
};   // 77.6 KB -> 2 blocks/CU

#define K7_MFMA3(ACC, AFH, AFL, BH, BL) \
  ACC = __builtin_amdgcn_mfma_f32_16x16x32_f16(AFL, BH, ACC, 0,0,0); \
  ACC = __builtin_amdgcn_mfma_f32_16x16x32_f16(AFH, BL, ACC, 0,0,0); \
  ACC = __builtin_amdgcn_mfma_f32_16x16x32_f16(AFH, BH, ACC, 0,0,0);

struct Bset { f16x8 h0,h1,h2,h3,l0,l1,l2,l3; };

DI void loadB(Bset& s, const _Float16* bph, const _Float16* bpl, int t){
  const _Float16* ph = bph + t*16384;
  const _Float16* pl = bpl + t*16384;
  s.h0 = *(const f16x8*)(ph);       s.h1 = *(const f16x8*)(ph+512);
  s.h2 = *(const f16x8*)(ph+1024);  s.h3 = *(const f16x8*)(ph+1536);
  s.l0 = *(const f16x8*)(pl);       s.l1 = *(const f16x8*)(pl+512);
  s.l2 = *(const f16x8*)(pl+1024);  s.l3 = *(const f16x8*)(pl+1536);
}

template<int MT>
DI void stepMFMA(f32x4 acc[][4], const _Float16* Ah, const _Float16* Al,
                 const Bset& B, int t, int ln){
  #pragma unroll
  for(int mt=0; mt<MT; ++mt){
    int off = (mt*16 + t)*512 + ((ln + t)&63)*8;
    f16x8 fh = *(const f16x8*)&Ah[off];
    f16x8 fl = *(const f16x8*)&Al[off];
    K7_MFMA3(acc[mt][0], fh, fl, B.h0, B.l0)
    K7_MFMA3(acc[mt][1], fh, fl, B.h1, B.l1)
    K7_MFMA3(acc[mt][2], fh, fl, B.h2, B.l2)
    K7_MFMA3(acc[mt][3], fh, fl, B.h3, B.l3)
  }
}

template<int MT, int K0>
DI void k7_body(int bn, const float* F, const float* AO, const float* attw,
                const _Float16* w1hi, const _Float16* w1lo,
                const float* b1p, const float* lng, const float* lnb,
                const float* w2, const float* b2p,
                const float* Svws, const float* wsumws,
                float* Qpws, K7Smem& sm){
  int b = bn/196, n = bn - b*196;
  int tid = threadIdx.x; int w = tid>>6, ln = tid&63;
  int col = ln&15, quad = ln>>4;
  const float* AObase = AO + (size_t)b*77*512;
  sm.b1s[tid] = b1p[tid]; sm.gs[tid] = lng[tid]; sm.bs[tid] = lnb[tid];
  if(tid<80) sm.wvS[tid] = (tid<77)? attw[((size_t)(b*77+tid))*196+n] : 0.f;
  __syncthreads();

  // ---- stage clean (hi/lo) for MT*16 rows into LDS; this thread owns fixed d0
  {
    int d0 = (tid&63)*8;            // fixed k-slice for this thread
    int r0 = tid>>6;                // base row 0..7 (+8 per step)
    int t  = d0>>5;
    int k8 = (d0&31)>>3;
    float4 f0 = *(const float4*)&F[(size_t)bn*512 + d0];
    float4 f1 = *(const float4*)&F[(size_t)bn*512 + d0+4];
    float4 sv0 = *(const float4*)&Svws[(size_t)bn*512 + d0];
    float4 sv1 = *(const float4*)&Svws[(size_t)bn*512 + d0+4];
    float fk[8] = {f0.x*1024.f,f0.y*1024.f,f0.z*1024.f,f0.w*1024.f,
                   f1.x*1024.f,f1.y*1024.f,f1.z*1024.f,f1.w*1024.f};
    float sv[8] = {sv0.x,sv0.y,sv0.z,sv0.w,sv1.x,sv1.y,sv1.z,sv1.w};
    #pragma unroll
    for(int it=0; it<MT*2; ++it){
      int row = r0 + it*8;          // local row 0..MT*16-1
      int grow = K0 + row;
      bool ok = grow < 77;
      int rl = ok ? grow : 0;
      float wm = ok ? sm.wvS[grow] : 0.f;
      const float* ap = AObase + (size_t)rl*512 + d0;
      float4 a0 = *(const float4*)ap;
      float4 a1 = *(const float4*)(ap+4);
      float av[8] = {a0.x,a0.y,a0.z,a0.w,a1.x,a1.y,a1.z,a1.w};
      f16x8 hfrag, lfrag;
      #pragma unroll
      for(int i=0;i<8;++i){
        float c = ok ? fk[i]*(wm*av[i] - sv[i]) : 0.f;
        _Float16 h = (_Float16)c;
        hfrag[i] = h;
        lfrag[i] = (_Float16)(c - (float)h);
      }
      int lane = (row&15) | (k8<<4);
      int pos = (lane + t)&63;
      int idx = (((row>>4)*16 + t)*512) + pos*8;
      *(f16x8*)&sm.Ah[idx] = hfrag;
      *(f16x8*)&sm.Al[idx] = lfrag;
    }
  }
  __syncthreads();
  // ---- barrier-free t-loop: A from LDS, B depth-2 prefetch from global ----
  f32x4 acc[MT][4];
  #pragma unroll
  for(int mt=0;mt<MT;++mt)
    #pragma unroll
    for(int jj=0;jj<4;++jj) acc[mt][jj] = (f32x4){0.f,0.f,0.f,0.f};

  const _Float16* bph = w1hi + ((w*4)*64 + ln)*8;  // +512 per jj, +16384 per t
  const _Float16* bpl = w1lo + ((w*4)*64 + ln)*8;

  Bset s0, s1, s2, s3;
  loadB(s0, bph, bpl, 0);
  loadB(s1, bph, bpl, 1);
  #pragma unroll 1
  for(int tt=0; tt<16; tt+=4){
    loadB(s2, bph, bpl, tt+2);
    stepMFMA<MT>(acc, sm.Ah, sm.Al, s0, tt, ln);
    loadB(s3, bph, bpl, tt+3);
    stepMFMA<MT>(acc, sm.Ah, sm.Al, s1, tt+1, ln);
    if(tt+4<16) loadB(s0, bph, bpl, tt+4);
    stepMFMA<MT>(acc, sm.Ah, sm.Al, s2, tt+2, ln);
    if(tt+5<16) loadB(s1, bph, bpl, tt+5);
    stepMFMA<MT>(acc, sm.Ah, sm.Al, s3, tt+3, ln);
  }

  const float UNS = 1.f/65536.f;
  #pragma unroll
  for(int mt=0;mt<MT;++mt){
    float s[4]={0.f,0.f,0.f,0.f}, q[4]={0.f,0.f,0.f,0.f};
    #pragma unroll
    for(int jj=0;jj<4;++jj){
      int j = w*64 + jj*16 + col; float bj = sm.b1s[j];
      #pragma unroll
      for(int r=0;r<4;++r){
        float h = acc[mt][jj][r]*UNS + bj;
        s[r]+=h; q[r]+=h*h;
      }
    }
    #pragma unroll
    for(int r=0;r<4;++r){
      #pragma unroll
      for(int o=1;o<16;o<<=1){ s[r]+=__shfl_xor(s[r],o,64); q[r]+=__shfl_xor(q[r],o,64); }
    }
    if(col==0){
      #pragma unroll
      for(int r=0;r<4;++r){ int row = mt*16+quad*4+r; sm.redS[w][row]=s[r]; sm.redQ[w][row]=q[r]; }
    }
  }
  __syncthreads();
  if(tid<MT*16){
    float s=0.f,q=0.f;
    #pragma unroll
    for(int ww=0;ww<8;++ww){ s+=sm.redS[ww][tid]; q+=sm.redQ[ww][tid]; }
    float mu = s*(1.f/512.f);
    float var = q*(1.f/512.f)-mu*mu;
    sm.muA[tid]=mu; sm.rsA[tid]=1.f/sqrtf(fmaxf(var,0.f)+1e-5f);
  }
  __syncthreads();
  float gp[4]={0.f,0.f,0.f,0.f};
  #pragma unroll
  for(int mt=0;mt<MT;++mt){
    #pragma unroll
    for(int r=0;r<4;++r){
      int lr = mt*16+quad*4+r;
      float mu=sm.muA[lr], rs=sm.rsA[lr], wk=sm.wvS[K0+lr];
      #pragma unroll
      for(int jj=0;jj<4;++jj){
        int j = w*64 + jj*16 + col;
        float h = acc[mt][jj][r]*UNS + sm.b1s[j];
        float x = (h-mu)*rs;
        float y = x*sm.gs[j]+sm.bs[j];
        float gl = 0.5f*y*(1.f+erff(y*0.70710678118654752f));
        gp[jj] += wk*gl;
      }
    }
  }
  #pragma unroll
  for(int jj=0;jj<4;++jj){ gp[jj]+=__shfl_xor(gp[jj],16,64); gp[jj]+=__shfl_xor(gp[jj],32,64); }
  if(ln<16){
    #pragma unroll
    for(int jj=0;jj<4;++jj) sm.gfin[w*64 + jj*16 + ln] = gp[jj];
  }
  __syncthreads();
  if(tid<320){ int m=tid>>4, seg=tid&15; float p=0.f;
    for(int u=0;u<32;++u){ int uu=(u+seg)&31; int j=seg*32+uu;   // rotated: per-lane distinct banks
      p += sm.gfin[j]*w2[m*512+j]; }
    sm.qred[m*16+seg]=p; }
  __syncthreads();
  if(tid<20){ float s=0.f;
    for(int seg=0;seg<16;++seg) s+=sm.qred[tid*16+seg];
    if(K0==0) s += b2p[tid]*wsumws[bn];          // bias term once, in third 0
    Qpws[(size_t)bn*60 + (K0==0?0:(K0==32?20:40)) + tid]=s; }
}

__global__
__attribute__((amdgpu_flat_work_group_size(512,512)))
void k7_mlp(const float* F, const float* AO, const float* attw,
            const _Float16* w1hi, const _Float16* w1lo,
            const float* b1p, const float* lng, const float* lnb,
            const float* w2, const float* b2p,
            const float* Svws, const float* wsumws,
            float* Qpws){
  __shared__ K7Smem sm;
  int bid = blockIdx.x;
  int bn = bid/3;
  int third = bid - bn*3;
  if(third==0)      k7_body<2,0 >(bn,F,AO,attw,w1hi,w1lo,b1p,lng,lnb,w2,b2p,Svws,wsumws,Qpws,sm);
  else if(third==1) k7_body<2,32>(bn,F,AO,attw,w1hi,w1lo,b1p,lng,lnb,w2,b2p,Svws,wsumws,Qpws,sm);
  else              k7_body<1,64>(bn,F,AO,attw,w1hi,w1lo,b1p,lng,lnb,w2,b2p,Svws,wsumws,Qpws,sm);
}

// ---------------- K8: per-(b,n) top-51 mask + normalize -> out1 ----------------
__global__ __launch_bounds__(256) void k8_topk(const float* F, const float* T,
                                               const float* Qpws, float* out1){
  int bn = blockIdx.x; int tid = threadIdx.x;
  int w = tid>>6, ln = tid&63;
  __shared__ float Fv[512];
  __shared__ float QpS[20];
  __shared__ float ninv[20];
  __shared__ unsigned char selb[20][64];
  for(int e=tid;e<512;e+=256) Fv[e]=F[(size_t)bn*512+e];
  if(tid<20) QpS[tid]=Qpws[(size_t)bn*60+tid] + Qpws[(size_t)bn*60+20+tid] + Qpws[(size_t)bn*60+40+tid];
  __syncthreads();
  for(int rr=0; rr<5; ++rr){
    int m = rr*4 + w;
    float qv[8]; uint key[8];
    const float4* tp = (const float4*)(T + (size_t)m*512 + ln*8);
    float4 t0 = tp[0], t1 = tp[1];
    float tf[8] = {t0.x,t0.y,t0.z,t0.w,t1.x,t1.y,t1.z,t1.w};
    float qp = QpS[m];
    #pragma unroll
    for(int i=0;i<8;++i){ float p = Fv[ln*8+i]*tf[i]; qv[i]=p*qp;
      key[i]=__float_as_uint(qv[i])&0x7fffffffu; }
    uint th=0u;
    for(int bit=30; bit>=0; --bit){
      uint cand = th | (1u<<bit);
      int c=0;
      #pragma unroll
      for(int i=0;i<8;++i) c += (int)__popcll(__ballot(key[i]>=cand));
      if(c>=51) th=cand;
    }
    int cg=0;
    #pragma unroll
    for(int i=0;i<8;++i) cg += (int)__popcll(__ballot(key[i]>th));
    int rneed = 51-cg;
    int eqc=0;
    #pragma unroll
    for(int i=0;i<8;++i) eqc += (key[i]==th);
    int pre=eqc;
    for(int o=1;o<64;o<<=1){ int v=__shfl_up(pre,o,64); if(ln>=o) pre+=v; }
    pre -= eqc;
    unsigned char mbits=0; float ss=0.f; int rk=pre;
    #pragma unroll
    for(int i=0;i<8;++i){
      bool s;
      if(key[i]>th) s=true;
      else if(key[i]==th){ s = (rk<rneed); rk++; }
      else s=false;
      if(s){ mbits |= (unsigned char)(1u<<i); ss += qv[i]*qv[i]; }
    }
    ss = wsumf(ss);
    if(ln==0) ninv[m] = 1.f/fmaxf(sqrtf(ss),1e-6f);
    selb[m][ln]=mbits;
  }
  __syncthreads();
  size_t base=(size_t)bn*10240;
  for(int e=tid;e<10240;e+=256){
    int d=e/20, mm=e-d*20;
    float val=0.f;
    if((selb[mm][d>>3]>>(d&7))&1){
      val = Fv[d]*T[(size_t)mm*512+d]*QpS[mm]*ninv[mm];
    }
    out1[base+e]=val;
  }
}

extern "C" void kernel_launch(void* const* d_in, const int* in_sizes, int n_in,
                              void* d_out, int out_size, void* d_ws, size_t ws_size,
                              hipStream_t stream){
  const float* F    = (const float*)d_in[0];
  const float* text = (const float*)d_in[1];
  const float* ipw  = (const float*)d_in[2];
  const float* ipb  = (const float*)d_in[3];
  const float* outw = (const float*)d_in[4];
  const float* outb = (const float*)d_in[5];
  const float* g1   = (const float*)d_in[6];
  const float* b1   = (const float*)d_in[7];
  const float* g2   = (const float*)d_in[8];
  const float* b2   = (const float*)d_in[9];
  const float* mw1  = (const float*)d_in[10];
  const float* mb1  = (const float*)d_in[11];
  const float* mlg  = (const float*)d_in[12];
  const float* mlb  = (const float*)d_in[13];
  const float* mw2  = (const float*)d_in[14];
  const float* mb2  = (const float*)d_in[15];
  const float* tmpl = (const float*)d_in[16];
  float* ws = (float*)d_ws;
  float* WT   = ws;
  float* OWT  = ws +  786432;
  float* qws  = ws + 1048576;
  float* kmat = ws + 1088000;
  float* vmat = ws + 1890816;
  float* attf = ws + 2693632;
  float* attw = ws + 3659520;
  float* ctx  = ws + 3780256;
  float* AO   = ws + 4095648;
  _Float16* w1hi = (_Float16*)(ws + 4473760);
  _Float16* w1lo = (_Float16*)(ws + 4604832);
  // dead-region reuse:
  float* wsum = ws + 1048576;   // old qws region (dead after k3)
  float* Sv   = ws + 1088000;   // old kmat region (dead after k3, exact fit)
  float* Qp   = ws +  786432;   // old OWT region (dead after k6; need 94080 fl <= 262144)
  float* out1 = (float*)d_out;
  float* out2 = out1 + 16056320;

  hipLaunchKernelGGL(k0_transpose, dim3(2048), dim3(256), 0, stream, ipw, outw, mw1, WT, OWT, w1hi, w1lo);
  hipLaunchKernelGGL(k1_q,   dim3(154), dim3(256), 0, stream, text, ipb, g1, b1, WT, qws);
  hipLaunchKernelGGL(k2_kv,  dim3(392), dim3(512), 0, stream, F, ipb, g1, b1, WT, kmat, vmat);
  hipLaunchKernelGGL(k3_attn,dim3(640), dim3(256), 0, stream, qws, kmat, attf);
  hipLaunchKernelGGL(k4_ctx, dim3(640), dim3(256), 0, stream, attf, vmat, ctx);
  hipLaunchKernelGGL(k5_attw,dim3(472), dim3(256), 0, stream, attf, attw, out2);
  hipLaunchKernelGGL(k6_ao,  dim3(77),  dim3(512), 0, stream, ctx, OWT, outb, g2, b2, AO);
  hipLaunchKernelGGL(k6b_sv, dim3(200), dim3(512), 0, stream, AO, attw, Sv, wsum);
  hipLaunchKernelGGL(k7_mlp, dim3(4704),dim3(512), 0, stream, F, AO, attw, w1hi, w1lo, mb1, mlg, mlb, mw2, mb2, Sv, wsum, Qp);
  hipLaunchKernelGGL(k8_topk,dim3(1568),dim3(256), 0, stream, F, tmpl, Qp, out1);
}

// Round 8
// 625.395 us; speedup vs baseline: 1.4874x; 1.0698x over previous
//
#include <hip/hip_runtime.h>
#include <hip/hip_bf16.h>
#include <math.h>

// B=8 N=196 D=512 M=20 K=77 H=8 hd=64, keep=51.  All inputs/outputs fp32.
// out1 = Qs/nrm (B,N,D,M) 16,056,320 fl; out2 = attn_weights (B,K,N) 120,736 fl
// Workspace layout: see kernel_launch. Dead-region reuse:
//   wsum -> qws (@1048576, dead after k3), Sv -> kmat (@1088000, dead after k3),
//   Qp -> OWT (@786432, dead after k6).
//
// R14 (post-mortem R13: depth-2 B-prefetch pushed arch VGPR to 100; gfx950
// unified budget arch+AGPR => ~136/wave => 3 waves/SIMD < 4 needed for two
// 8-wave blocks => 1 blk/CU, Occ 21%, k7 267->371us REGRESSION. Budget rule:
// arch + 32 AGPR <= 128 => max 2 B-sets. k2-split/k8-ballot/qred-rotation
// from R13 gained ~123us elsewhere - keep them):
//  k7 t-loop reverted to R12's proven 2-Bset ping-pong (267us, VGPR 64).

typedef unsigned int uint;
typedef _Float16 f16x8 __attribute__((ext_vector_type(8)));
typedef float f32x4 __attribute__((ext_vector_type(4)));

#define DI __device__ __forceinline__

DI float wsumf(float v){ for(int o=32;o>0;o>>=1) v += __shfl_xor(v,o,64); return v; }
DI int   wsumi(int v){ for(int o=32;o>0;o>>=1) v += __shfl_xor(v,o,64); return v; }
DI float wmaxf(float v){ for(int o=32;o>0;o>>=1) v = fmaxf(v,__shfl_xor(v,o,64)); return v; }

// ---------------- K0: tiled transposes + W1 split/swizzle ----------------
__global__ __launch_bounds__(256) void k0_transpose(const float* ipw, const float* ow, const float* mw1,
                             float* WT, float* OWT, _Float16* w1hi, _Float16* w1lo){
  int bid = blockIdx.x;
  if(bid < 768){
    __shared__ float t[32][33];
    int tdin = bid & 15, tdout = bid >> 4;
    int tx = threadIdx.x & 31, ty = threadIdx.x >> 5;
    int dout0 = tdout*32, din0 = tdin*32;
    for(int r=ty; r<32; r+=8) t[r][tx] = ipw[(size_t)(dout0+r)*512 + din0+tx];
    __syncthreads();
    for(int r=ty; r<32; r+=8) WT[(size_t)(din0+r)*1536 + dout0+tx] = t[tx][r];
  } else if(bid < 1024){
    __shared__ float t[32][33];
    int b2 = bid - 768;
    int tdin = b2 & 15, tdout = b2 >> 4;
    int tx = threadIdx.x & 31, ty = threadIdx.x >> 5;
    int dout0 = tdout*32, din0 = tdin*32;
    for(int r=ty; r<32; r+=8) t[r][tx] = ow[(size_t)(dout0+r)*512 + din0+tx];
    __syncthreads();
    for(int r=ty; r<32; r+=8) OWT[(size_t)(din0+r)*512 + dout0+tx] = t[tx][r];
  } else {
    int i3 = (bid-1024)*256 + threadIdx.x;
    int t = i3&7, ln = (i3>>3)&63, J = (i3>>9)&31, T = i3>>14;
    int j = J*16 + (ln&15);
    int d = T*32 + ((ln>>4)<<3) + t;
    float w = mw1[j*512 + d] * 64.0f;
    _Float16 hi = (_Float16)w;
    _Float16 lo = (_Float16)(w - (float)hi);
    w1hi[i3] = hi; w1lo[i3] = lo;
  }
}

// ---------------- K1: q = LN(text) @ Wq^T + bq  (154 blocks: k x half) ----------------
__global__ __launch_bounds__(256) void k1_q(const float* text, const float* ipb,
                                            const float* g1, const float* b1p,
                                            const float* WT, float* qws){
  int k = blockIdx.x >> 1, half = blockIdx.x & 1;
  int tid = threadIdx.x;
  __shared__ float xln[512];
  __shared__ float rA[4], rB[4];
  float x0 = text[k*512+tid], x1 = text[k*512+256+tid];
  float s1 = wsumf(x0+x1), s2 = wsumf(x0*x0+x1*x1);
  int w = tid>>6, ln = tid&63;
  if(!ln){ rA[w]=s1; rB[w]=s2; }
  __syncthreads();
  float mu = (rA[0]+rA[1]+rA[2]+rA[3])*(1.f/512.f);
  float var = (rB[0]+rB[1]+rB[2]+rB[3])*(1.f/512.f) - mu*mu;
  float rs = 1.f/sqrtf(fmaxf(var,0.f) + 1e-5f);
  xln[tid]     = (x0-mu)*rs*g1[tid]     + b1p[tid];
  xln[tid+256] = (x1-mu)*rs*g1[tid+256] + b1p[tid+256];
  __syncthreads();
  int d = half*256 + tid;
  float a0=0.f,a1=0.f,a2=0.f,a3=0.f;   // 4 independent chains for ILP
  for(int din=0; din<512; din+=4){
    a0 += xln[din  ] * WT[(din  )*1536 + d];
    a1 += xln[din+1] * WT[(din+1)*1536 + d];
    a2 += xln[din+2] * WT[(din+2)*1536 + d];
    a3 += xln[din+3] * WT[(din+3)*1536 + d];
  }
  qws[k*512+d] = ipb[d] + ((a0+a1)+(a2+a3));
}

// ---------------- K2: k = LN(F)@Wk^T+bk, v = F@Wv^T+bv  (4 rows/block, 392 blocks) ----
__global__ __launch_bounds__(512) void k2_kv(const float* F, const float* ipb,
                                             const float* g1, const float* b1p,
                                             const float* WT, float* kmat, float* vmat){
  int r0 = blockIdx.x*4; int tid = threadIdx.x;
  __shared__ float xs[4][512];
  __shared__ float xl[4][512];
  __shared__ float red[4][64];
  __shared__ float mu4[4], rs4[4];
  for(int e=tid; e<2048; e+=512){ int r=e>>9, d=e&511; xs[r][d] = F[(size_t)(r0+r)*512 + d]; }
  __syncthreads();
  {
    float s=0.f, q=0.f; int r=0, t=0;
    if(tid<256){
      r = tid>>6; t = tid&63;
      for(int i=0;i<8;++i){ float v = xs[r][t+64*i]; s+=v; q+=v*v; }
      red[r][t] = s;
    }
    __syncthreads();
    if(tid<4){ float ss=0; for(int i=0;i<64;++i) ss+=red[tid][i]; mu4[tid]=ss*(1.f/512.f); }
    __syncthreads();
    if(tid<256) red[r][t] = q;
    __syncthreads();
    if(tid<4){ float qq=0; for(int i=0;i<64;++i) qq+=red[tid][i];
      float m=mu4[tid]; rs4[tid]=1.f/sqrtf(fmaxf(qq*(1.f/512.f)-m*m,0.f)+1e-5f); }
    __syncthreads();
  }
  for(int e=tid; e<2048; e+=512){ int r=e>>9, d=e&511;
    xl[r][d] = (xs[r][d]-mu4[r])*rs4[r]*g1[d] + b1p[d]; }
  __syncthreads();
  int d=tid;
  float ak[4], av[4];
  float bk=ipb[512+d], bv=ipb[1024+d];
  #pragma unroll
  for(int r=0;r<4;++r){ ak[r]=bk; av[r]=bv; }
  for(int din=0; din<512; din+=4){
    float wk[4], wv[4];
    #pragma unroll
    for(int u=0;u<4;++u){ wk[u]=WT[(din+u)*1536+512+d]; wv[u]=WT[(din+u)*1536+1024+d]; }
    #pragma unroll
    for(int r=0;r<4;++r){
      float4 a4 = *(const float4*)&xl[r][din];
      float4 x4 = *(const float4*)&xs[r][din];
      ak[r] += a4.x*wk[0]+a4.y*wk[1]+a4.z*wk[2]+a4.w*wk[3];
      av[r] += x4.x*wv[0]+x4.y*wv[1]+x4.z*wv[2]+x4.w*wv[3];
    }
  }
  #pragma unroll
  for(int r=0;r<4;++r){
    size_t base = (size_t)(r0+r)*512;
    kmat[base+d]=ak[r]; vmat[base+d]=av[r];
  }
}

// ---------------- K3: scores + softmax (640 blocks: kc x b x h) ----------------
__global__ __launch_bounds__(256) void k3_attn(const float* qws, const float* kmat, float* attf){
  int bid = blockIdx.x;
  int kc = bid>>6, b = (bid>>3)&7, h = bid&7;
  int tid = threadIdx.x; int n = tid; int w = tid>>6, ln = tid&63;
  __shared__ float qb[8][64];
  __shared__ float rM[8][4], rS[8][4];
  float4 kr[16];
  if(n < 196){
    const float4* kp = (const float4*)(kmat + ((size_t)(b*196+n))*512 + h*64);
    #pragma unroll
    for(int j=0;j<16;++j) kr[j] = kp[j];
  }
  int kbase = kc*8;
  for(int e=tid; e<512; e+=256){ int kk=e>>6, j=e&63; int k=kbase+kk;
    qb[kk][j] = (k<77)? qws[k*512 + h*64 + j] : 0.f; }
  __syncthreads();
  float sc[8];
  #pragma unroll
  for(int kk=0;kk<8;++kk){
    float s = 0.f;
    if(n<196){
      const float4* q4 = (const float4*)qb[kk];
      #pragma unroll
      for(int j=0;j<16;++j){ float4 q = q4[j];
        s += q.x*kr[j].x + q.y*kr[j].y + q.z*kr[j].z + q.w*kr[j].w; }
      sc[kk] = s*0.125f;
    } else sc[kk] = -INFINITY;
  }
  #pragma unroll
  for(int kk=0;kk<8;++kk){ float m = wmaxf(sc[kk]); if(!ln) rM[kk][w]=m; }
  __syncthreads();
  float ex[8];
  #pragma unroll
  for(int kk=0;kk<8;++kk){
    float m = fmaxf(fmaxf(rM[kk][0],rM[kk][1]),fmaxf(rM[kk][2],rM[kk][3]));
    float e = expf(sc[kk]-m);
    ex[kk]=e;
    float s = wsumf(e); if(!ln) rS[kk][w]=s;
  }
  __syncthreads();
  #pragma unroll
  for(int kk=0;kk<8;++kk){
    int k = kbase+kk;
    if(k<77 && n<196){
      float tot = rS[kk][0]+rS[kk][1]+rS[kk][2]+rS[kk][3];
      attf[(((size_t)(b*8+h))*77 + k)*196 + n] = ex[kk]/tot;
    }
  }
}

// ---------------- K4: ctx = attn @ v (640 blocks: kc x b x h) ----------------
__global__ __launch_bounds__(256) void k4_ctx(const float* attf, const float* vmat, float* ctx){
  int bid = blockIdx.x;
  int kc = bid>>6, b = (bid>>3)&7, h = bid&7;
  int tid = threadIdx.x; int ng = tid>>6, j = tid&63;
  __shared__ float vT[196][64];
  __shared__ float aT[8][196];
  __shared__ float red[8][4][64];
  for(int e=tid; e<196*16; e+=256){ int n=e>>4, jc=e&15;
    const float4* vp = (const float4*)(vmat + ((size_t)(b*196+n))*512 + h*64);
    *(float4*)&vT[n][jc*4] = vp[jc];
  }
  int kbase=kc*8;
  for(int e=tid; e<8*196; e+=256){ int kk=e/196, n=e-kk*196; int k=kbase+kk;
    aT[kk][n] = (k<77)? attf[(((size_t)(b*8+h))*77+k)*196+n] : 0.f; }
  __syncthreads();
  float vr[49];
  #pragma unroll
  for(int t=0;t<49;++t) vr[t] = vT[ng*49+t][j];
  #pragma unroll
  for(int kk=0;kk<8;++kk){
    float p=0.f;
    #pragma unroll
    for(int t=0;t<49;++t) p += aT[kk][ng*49+t]*vr[t];
    red[kk][ng][j]=p;
  }
  __syncthreads();
  for(int e=tid; e<512; e+=256){ int kk=e>>6, j2=e&63; int k=kbase+kk;
    if(k<77){
      float s = red[kk][0][j2]+red[kk][1][j2]+red[kk][2][j2]+red[kk][3][j2];
      ctx[((size_t)(b*77+k))*512 + h*64 + j2] = s;
    } }
}

// ---------------- K5: attn_weights = mean over H ----------------
__global__ void k5_attw(const float* attf, float* attw, float* out2){
  int idx = blockIdx.x*256+threadIdx.x;
  if(idx >= 8*77*196) return;
  int b = idx / (77*196); int rem = idx - b*(77*196);
  float s=0.f;
  #pragma unroll
  for(int h=0;h<8;++h) s += attf[((size_t)(b*8+h))*77*196 + rem];
  s *= 0.125f;
  attw[idx]=s; out2[idx]=s;
}

// ---------------- K6: AO = LN2(ctx @ out_w^T + out_b)  (512 thr) ----------------
__global__ __launch_bounds__(512) void k6_ao(const float* ctx, const float* OWT,
                                             const float* ob, const float* g2, const float* b2p,
                                             float* AO){
  int R0 = blockIdx.x*8; int tid = threadIdx.x;
  __shared__ float xs[8][512];
  __shared__ float ao[8][512];
  __shared__ float red[8][64];
  __shared__ float mu8[8], rs8[8];
  for(int e=tid;e<4096;e+=512){ int r=e>>9,d=e&511; xs[r][d]=ctx[(size_t)(R0+r)*512+d]; }
  __syncthreads();
  int d=tid;
  float a[8]; float obv=ob[d];
  #pragma unroll
  for(int r=0;r<8;++r) a[r]=obv;
  for(int din=0;din<512;din+=4){
    float wv[4];
    #pragma unroll
    for(int u=0;u<4;++u) wv[u]=OWT[(din+u)*512+d];
    #pragma unroll
    for(int r=0;r<8;++r){
      float4 x4 = *(const float4*)&xs[r][din];
      a[r] += x4.x*wv[0]+x4.y*wv[1]+x4.z*wv[2]+x4.w*wv[3];
    }
  }
  #pragma unroll
  for(int r=0;r<8;++r) ao[r][d]=a[r];
  __syncthreads();
  {
    int r=tid>>6,t=tid&63; float s=0.f,q=0.f;
    for(int i=0;i<8;++i){ float v=ao[r][t+64*i]; s+=v; q+=v*v; }
    red[r][t]=s; __syncthreads();
    if(tid<8){ float ss=0; for(int i=0;i<64;++i) ss+=red[tid][i]; mu8[tid]=ss*(1.f/512.f); }
    __syncthreads(); red[r][t]=q; __syncthreads();
    if(tid<8){ float qq=0; for(int i=0;i<64;++i) qq+=red[tid][i];
      float m=mu8[tid]; rs8[tid]=1.f/sqrtf(fmaxf(qq*(1.f/512.f)-m*m,0.f)+1e-5f); }
    __syncthreads();
  }
  for(int e=tid;e<4096;e+=512){ int r=e>>9,dd=e&511;
    AO[(size_t)(R0+r)*512+dd] = (ao[r][dd]-mu8[r])*rs8[r]*g2[dd] + b2p[dd]; }
}

// ---------------- K6b: Sv = (1/77) attw^T @ AO per (b, 8-n tile); wsum ---------
__global__ __launch_bounds__(512) void k6b_sv(const float* AO, const float* attw,
                                              float* Svws, float* wsumws){
  int bid = blockIdx.x;
  int b = bid/25, nt = bid - b*25;
  int n0 = nt*8;
  int tid = threadIdx.x;
  __shared__ float wsK[80][8];
  for(int e=tid; e<640; e+=512){ int k=e>>3, r=e&7; int n=n0+r;
    wsK[k][r] = (k<77 && n<196)? attw[((size_t)(b*77+k))*196 + n] : 0.f; }
  __syncthreads();
  if(tid<8){ int n=n0+tid;
    if(n<196){ float s=0.f;
      for(int k=0;k<77;++k) s+=wsK[k][tid];
      wsumws[b*196+n]=s; } }
  int d = tid;
  float acc[8];
  #pragma unroll
  for(int r=0;r<8;++r) acc[r]=0.f;
  const float* aob = AO + (size_t)b*77*512 + d;
  for(int k=0;k<77;++k){
    float a = aob[(size_t)k*512];
    #pragma unroll
    for(int r=0;r<8;++r) acc[r] += wsK[k][r]*a;
  }
  #pragma unroll
  for(int r=0;r<8;++r){ int n=n0+r; if(n<196)
    Svws[((size_t)(b*196+n))*512 + d] = acc[r]*(1.f/77.f); }
}

// ---------------- K7: per-(b,n,third) fused MLP; A LDS-resident, barrier-free t-loop
// 3-way row split: thirds (MT=2,2,1). A-LDS 64KB (MT=2), struct 77.6KB ->
// 2 blocks/CU -> unified reg budget per wave: arch + 32 AGPR <= 128.
// t-loop: 2-Bset ping-pong (R12-proven: VGPR 64 arch + 32 AGPR = 96, fits),
// ds_read A, MFMA, zero barriers. Depth-2 prefetch REGRESSED (R13: 100 arch
// + 32 AGPR > 128 -> 1 blk/CU) - do not reintroduce.
struct __align__(16) K7Smem {
  _Float16 Ah[2*16*512];    // [mt][t][pos 0..63][8], pos=(lane+t)&63
  _Float16 Al[2*16*512];
  float b1s[512], gs[512], bs[512];
  float wvS[80];
  float redS[8][32], redQ[8][32];
  float muA[32], rsA[32];
  float gfin[512];
  float qred[320];
};   // 77.6 KB -> 2 blocks/CU

#define K7_MFMA3(ACC, AFH, AFL, BH, BL) \
  ACC = __builtin_amdgcn_mfma_f32_16x16x32_f16(AFL, BH, ACC, 0,0,0); \
  ACC = __builtin_amdgcn_mfma_f32_16x16x32_f16(AFH, BL, ACC, 0,0,0); \
  ACC = __builtin_amdgcn_mfma_f32_16x16x32_f16(AFH, BH, ACC, 0,0,0);

struct Bset { f16x8 h0,h1,h2,h3,l0,l1,l2,l3; };

DI void loadB(Bset& s, const _Float16* bph, const _Float16* bpl, int t){
  const _Float16* ph = bph + t*16384;
  const _Float16* pl = bpl + t*16384;
  s.h0 = *(const f16x8*)(ph);       s.h1 = *(const f16x8*)(ph+512);
  s.h2 = *(const f16x8*)(ph+1024);  s.h3 = *(const f16x8*)(ph+1536);
  s.l0 = *(const f16x8*)(pl);       s.l1 = *(const f16x8*)(pl+512);
  s.l2 = *(const f16x8*)(pl+1024);  s.l3 = *(const f16x8*)(pl+1536);
}

template<int MT>
DI void stepMFMA(f32x4 acc[][4], const _Float16* Ah, const _Float16* Al,
                 const Bset& B, int t, int ln){
  #pragma unroll
  for(int mt=0; mt<MT; ++mt){
    int off = (mt*16 + t)*512 + ((ln + t)&63)*8;
    f16x8 fh = *(const f16x8*)&Ah[off];
    f16x8 fl = *(const f16x8*)&Al[off];
    K7_MFMA3(acc[mt][0], fh, fl, B.h0, B.l0)
    K7_MFMA3(acc[mt][1], fh, fl, B.h1, B.l1)
    K7_MFMA3(acc[mt][2], fh, fl, B.h2, B.l2)
    K7_MFMA3(acc[mt][3], fh, fl, B.h3, B.l3)
  }
}

template<int MT, int K0>
DI void k7_body(int bn, const float* F, const float* AO, const float* attw,
                const _Float16* w1hi, const _Float16* w1lo,
                const float* b1p, const float* lng, const float* lnb,
                const float* w2, const float* b2p,
                const float* Svws, const float* wsumws,
                float* Qpws, K7Smem& sm){
  int b = bn/196, n = bn - b*196;
  int tid = threadIdx.x; int w = tid>>6, ln = tid&63;
  int col = ln&15, quad = ln>>4;
  const float* AObase = AO + (size_t)b*77*512;
  sm.b1s[tid] = b1p[tid]; sm.gs[tid] = lng[tid]; sm.bs[tid] = lnb[tid];
  if(tid<80) sm.wvS[tid] = (tid<77)? attw[((size_t)(b*77+tid))*196+n] : 0.f;
  __syncthreads();

  // ---- stage clean (hi/lo) for MT*16 rows into LDS; this thread owns fixed d0
  {
    int d0 = (tid&63)*8;            // fixed k-slice for this thread
    int r0 = tid>>6;                // base row 0..7 (+8 per step)
    int t  = d0>>5;
    int k8 = (d0&31)>>3;
    float4 f0 = *(const float4*)&F[(size_t)bn*512 + d0];
    float4 f1 = *(const float4*)&F[(size_t)bn*512 + d0+4];
    float4 sv0 = *(const float4*)&Svws[(size_t)bn*512 + d0];
    float4 sv1 = *(const float4*)&Svws[(size_t)bn*512 + d0+4];
    float fk[8] = {f0.x*1024.f,f0.y*1024.f,f0.z*1024.f,f0.w*1024.f,
                   f1.x*1024.f,f1.y*1024.f,f1.z*1024.f,f1.w*1024.f};
    float sv[8] = {sv0.x,sv0.y,sv0.z,sv0.w,sv1.x,sv1.y,sv1.z,sv1.w};
    #pragma unroll
    for(int it=0; it<MT*2; ++it){
      int row = r0 + it*8;          // local row 0..MT*16-1
      int grow = K0 + row;
      bool ok = grow < 77;
      int rl = ok ? grow : 0;
      float wm = ok ? sm.wvS[grow] : 0.f;
      const float* ap = AObase + (size_t)rl*512 + d0;
      float4 a0 = *(const float4*)ap;
      float4 a1 = *(const float4*)(ap+4);
      float av[8] = {a0.x,a0.y,a0.z,a0.w,a1.x,a1.y,a1.z,a1.w};
      f16x8 hfrag, lfrag;
      #pragma unroll
      for(int i=0;i<8;++i){
        float c = ok ? fk[i]*(wm*av[i] - sv[i]) : 0.f;
        _Float16 h = (_Float16)c;
        hfrag[i] = h;
        lfrag[i] = (_Float16)(c - (float)h);
      }
      int lane = (row&15) | (k8<<4);
      int pos = (lane + t)&63;
      int idx = (((row>>4)*16 + t)*512) + pos*8;
      *(f16x8*)&sm.Ah[idx] = hfrag;
      *(f16x8*)&sm.Al[idx] = lfrag;
    }
  }
  __syncthreads();
  // ---- barrier-free t-loop: A from LDS, B 2-set ping-pong from global ----
  f32x4 acc[MT][4];
  #pragma unroll
  for(int mt=0;mt<MT;++mt)
    #pragma unroll
    for(int jj=0;jj<4;++jj) acc[mt][jj] = (f32x4){0.f,0.f,0.f,0.f};

  const _Float16* bph = w1hi + ((w*4)*64 + ln)*8;  // +512 per jj, +16384 per t
  const _Float16* bpl = w1lo + ((w*4)*64 + ln)*8;

  Bset s0, s1;
  loadB(s0, bph, bpl, 0);
  #pragma unroll 1
  for(int tt=0; tt<16; tt+=2){
    loadB(s1, bph, bpl, tt+1);                 // prefetch odd step
    stepMFMA<MT>(acc, sm.Ah, sm.Al, s0, tt, ln);
    if(tt+2<16) loadB(s0, bph, bpl, tt+2);     // prefetch next even step
    stepMFMA<MT>(acc, sm.Ah, sm.Al, s1, tt+1, ln);
  }

  const float UNS = 1.f/65536.f;
  #pragma unroll
  for(int mt=0;mt<MT;++mt){
    float s[4]={0.f,0.f,0.f,0.f}, q[4]={0.f,0.f,0.f,0.f};
    #pragma unroll
    for(int jj=0;jj<4;++jj){
      int j = w*64 + jj*16 + col; float bj = sm.b1s[j];
      #pragma unroll
      for(int r=0;r<4;++r){
        float h = acc[mt][jj][r]*UNS + bj;
        s[r]+=h; q[r]+=h*h;
      }
    }
    #pragma unroll
    for(int r=0;r<4;++r){
      #pragma unroll
      for(int o=1;o<16;o<<=1){ s[r]+=__shfl_xor(s[r],o,64); q[r]+=__shfl_xor(q[r],o,64); }
    }
    if(col==0){
      #pragma unroll
      for(int r=0;r<4;++r){ int row = mt*16+quad*4+r; sm.redS[w][row]=s[r]; sm.redQ[w][row]=q[r]; }
    }
  }
  __syncthreads();
  if(tid<MT*16){
    float s=0.f,q=0.f;
    #pragma unroll
    for(int ww=0;ww<8;++ww){ s+=sm.redS[ww][tid]; q+=sm.redQ[ww][tid]; }
    float mu = s*(1.f/512.f);
    float var = q*(1.f/512.f)-mu*mu;
    sm.muA[tid]=mu; sm.rsA[tid]=1.f/sqrtf(fmaxf(var,0.f)+1e-5f);
  }
  __syncthreads();
  float gp[4]={0.f,0.f,0.f,0.f};
  #pragma unroll
  for(int mt=0;mt<MT;++mt){
    #pragma unroll
    for(int r=0;r<4;++r){
      int lr = mt*16+quad*4+r;
      float mu=sm.muA[lr], rs=sm.rsA[lr], wk=sm.wvS[K0+lr];
      #pragma unroll
      for(int jj=0;jj<4;++jj){
        int j = w*64 + jj*16 + col;
        float h = acc[mt][jj][r]*UNS + sm.b1s[j];
        float x = (h-mu)*rs;
        float y = x*sm.gs[j]+sm.bs[j];
        float gl = 0.5f*y*(1.f+erff(y*0.70710678118654752f));
        gp[jj] += wk*gl;
      }
    }
  }
  #pragma unroll
  for(int jj=0;jj<4;++jj){ gp[jj]+=__shfl_xor(gp[jj],16,64); gp[jj]+=__shfl_xor(gp[jj],32,64); }
  if(ln<16){
    #pragma unroll
    for(int jj=0;jj<4;++jj) sm.gfin[w*64 + jj*16 + ln] = gp[jj];
  }
  __syncthreads();
  if(tid<320){ int m=tid>>4, seg=tid&15; float p=0.f;
    for(int u=0;u<32;++u){ int uu=(u+seg)&31; int j=seg*32+uu;   // rotated: per-lane distinct banks
      p += sm.gfin[j]*w2[m*512+j]; }
    sm.qred[m*16+seg]=p; }
  __syncthreads();
  if(tid<20){ float s=0.f;
    for(int seg=0;seg<16;++seg) s+=sm.qred[tid*16+seg];
    if(K0==0) s += b2p[tid]*wsumws[bn];          // bias term once, in third 0
    Qpws[(size_t)bn*60 + (K0==0?0:(K0==32?20:40)) + tid]=s; }
}

__global__
__attribute__((amdgpu_flat_work_group_size(512,512)))
void k7_mlp(const float* F, const float* AO, const float* attw,
            const _Float16* w1hi, const _Float16* w1lo,
            const float* b1p, const float* lng, const float* lnb,
            const float* w2, const float* b2p,
            const float* Svws, const float* wsumws,
            float* Qpws){
  __shared__ K7Smem sm;
  int bid = blockIdx.x;
  int bn = bid/3;
  int third = bid - bn*3;
  if(third==0)      k7_body<2,0 >(bn,F,AO,attw,w1hi,w1lo,b1p,lng,lnb,w2,b2p,Svws,wsumws,Qpws,sm);
  else if(third==1) k7_body<2,32>(bn,F,AO,attw,w1hi,w1lo,b1p,lng,lnb,w2,b2p,Svws,wsumws,Qpws,sm);
  else              k7_body<1,64>(bn,F,AO,attw,w1hi,w1lo,b1p,lng,lnb,w2,b2p,Svws,wsumws,Qpws,sm);
}

// ---------------- K8: per-(b,n) top-51 mask + normalize -> out1 ----------------
__global__ __launch_bounds__(256) void k8_topk(const float* F, const float* T,
                                               const float* Qpws, float* out1){
  int bn = blockIdx.x; int tid = threadIdx.x;
  int w = tid>>6, ln = tid&63;
  __shared__ float Fv[512];
  __shared__ float QpS[20];
  __shared__ float ninv[20];
  __shared__ unsigned char selb[20][64];
  for(int e=tid;e<512;e+=256) Fv[e]=F[(size_t)bn*512+e];
  if(tid<20) QpS[tid]=Qpws[(size_t)bn*60+tid] + Qpws[(size_t)bn*60+20+tid] + Qpws[(size_t)bn*60+40+tid];
  __syncthreads();
  for(int rr=0; rr<5; ++rr){
    int m = rr*4 + w;
    float qv[8]; uint key[8];
    const float4* tp = (const float4*)(T + (size_t)m*512 + ln*8);
    float4 t0 = tp[0], t1 = tp[1];
    float tf[8] = {t0.x,t0.y,t0.z,t0.w,t1.x,t1.y,t1.z,t1.w};
    float qp = QpS[m];
    #pragma unroll
    for(int i=0;i<8;++i){ float p = Fv[ln*8+i]*tf[i]; qv[i]=p*qp;
      key[i]=__float_as_uint(qv[i])&0x7fffffffu; }
    uint th=0u;
    for(int bit=30; bit>=0; --bit){
      uint cand = th | (1u<<bit);
      int c=0;
      #pragma unroll
      for(int i=0;i<8;++i) c += (int)__popcll(__ballot(key[i]>=cand));
      if(c>=51) th=cand;
    }
    int cg=0;
    #pragma unroll
    for(int i=0;i<8;++i) cg += (int)__popcll(__ballot(key[i]>th));
    int rneed = 51-cg;
    int eqc=0;
    #pragma unroll
    for(int i=0;i<8;++i) eqc += (key[i]==th);
    int pre=eqc;
    for(int o=1;o<64;o<<=1){ int v=__shfl_up(pre,o,64); if(ln>=o) pre+=v; }
    pre -= eqc;
    unsigned char mbits=0; float ss=0.f; int rk=pre;
    #pragma unroll
    for(int i=0;i<8;++i){
      bool s;
      if(key[i]>th) s=true;
      else if(key[i]==th){ s = (rk<rneed); rk++; }
      else s=false;
      if(s){ mbits |= (unsigned char)(1u<<i); ss += qv[i]*qv[i]; }
    }
    ss = wsumf(ss);
    if(ln==0) ninv[m] = 1.f/fmaxf(sqrtf(ss),1e-6f);
    selb[m][ln]=mbits;
  }
  __syncthreads();
  size_t base=(size_t)bn*10240;
  for(int e=tid;e<10240;e+=256){
    int d=e/20, mm=e-d*20;
    float val=0.f;
    if((selb[mm][d>>3]>>(d&7))&1){
      val = Fv[d]*T[(size_t)mm*512+d]*QpS[mm]*ninv[mm];
    }
    out1[base+e]=val;
  }
}

extern "C" void kernel_launch(void* const* d_in, const int* in_sizes, int n_in,
                              void* d_out, int out_size, void* d_ws, size_t ws_size,
                              hipStream_t stream){
  const float* F    = (const float*)d_in[0];
  const float* text = (const float*)d_in[1];
  const float* ipw  = (const float*)d_in[2];
  const float* ipb  = (const float*)d_in[3];
  const float* outw = (const float*)d_in[4];
  const float* outb = (const float*)d_in[5];
  const float* g1   = (const float*)d_in[6];
  const float* b1   = (const float*)d_in[7];
  const float* g2   = (const float*)d_in[8];
  const float* b2   = (const float*)d_in[9];
  const float* mw1  = (const float*)d_in[10];
  const float* mb1  = (const float*)d_in[11];
  const float* mlg  = (const float*)d_in[12];
  const float* mlb  = (const float*)d_in[13];
  const float* mw2  = (const float*)d_in[14];
  const float* mb2  = (const float*)d_in[15];
  const float* tmpl = (const float*)d_in[16];
  float* ws = (float*)d_ws;
  float* WT   = ws;
  float* OWT  = ws +  786432;
  float* qws  = ws + 1048576;
  float* kmat = ws + 1088000;
  float* vmat = ws + 1890816;
  float* attf = ws + 2693632;
  float* attw = ws + 3659520;
  float* ctx  = ws + 3780256;
  float* AO   = ws + 4095648;
  _Float16* w1hi = (_Float16*)(ws + 4473760);
  _Float16* w1lo = (_Float16*)(ws + 4604832);
  // dead-region reuse:
  float* wsum = ws + 1048576;   // old qws region (dead after k3)
  float* Sv   = ws + 1088000;   // old kmat region (dead after k3, exact fit)
  float* Qp   = ws +  786432;   // old OWT region (dead after k6; need 94080 fl <= 262144)
  float* out1 = (float*)d_out;
  float* out2 = out1 + 16056320;

  hipLaunchKernelGGL(k0_transpose, dim3(2048), dim3(256), 0, stream, ipw, outw, mw1, WT, OWT, w1hi, w1lo);
  hipLaunchKernelGGL(k1_q,   dim3(154), dim3(256), 0, stream, text, ipb, g1, b1, WT, qws);
  hipLaunchKernelGGL(k2_kv,  dim3(392), dim3(512), 0, stream, F, ipb, g1, b1, WT, kmat, vmat);
  hipLaunchKernelGGL(k3_attn,dim3(640), dim3(256), 0, stream, qws, kmat, attf);
  hipLaunchKernelGGL(k4_ctx, dim3(640), dim3(256), 0, stream, attf, vmat, ctx);
  hipLaunchKernelGGL(k5_attw,dim3(472), dim3(256), 0, stream, attf, attw, out2);
  hipLaunchKernelGGL(k6_ao,  dim3(77),  dim3(512), 0, stream, ctx, OWT, outb, g2, b2, AO);
  hipLaunchKernelGGL(k6b_sv, dim3(200), dim3(512), 0, stream, AO, attw, Sv, wsum);
  hipLaunchKernelGGL(k7_mlp, dim3(4704),dim3(512), 0, stream, F, AO, attw, w1hi, w1lo, mb1, mlg, mlb, mw2, mb2, Sv, wsum, Qp);
  hipLaunchKernelGGL(k8_topk,dim3(1568),dim3(256), 0, stream, F, tmpl, Qp, out1);
}